// Round 1
// baseline (596.862 us; speedup 1.0000x reference)
//
#include <hip/hip_runtime.h>
#include <math.h>

#define KK 8
#define EPSF 1e-9f

__device__ __forceinline__ float softplusf(float x) {
    return x > 0.0f ? x + log1pf(expf(-x)) : log1pf(expf(x));
}
__device__ __forceinline__ float sigmoidf_(float x) {
    return 1.0f / (1.0f + expf(-x));
}

// ---------------------------------------------------------------------------
// u = softplus(X @ gw + gb), w = sigmoid(X @ aw + ab), per (row, k)
// ---------------------------------------------------------------------------
__global__ __launch_bounds__(256)
void uw_kernel(const float* __restrict__ X, const float* __restrict__ gw,
               const float* __restrict__ gb, const float* __restrict__ aw,
               const float* __restrict__ ab, float* __restrict__ u,
               float* __restrict__ w, int rows, int F) {
    int t = blockIdx.x * 256 + threadIdx.x;
    if (t >= rows * KK) return;
    int row = t >> 3, k = t & 7;
    const float* xr = X + (size_t)row * F;
    float su = 0.f, sw = 0.f;
    for (int f = 0; f < F; f++) {
        float x = xr[f];
        su += x * gw[f * KK + k];
        sw += x * aw[f * KK + k];
    }
    u[t] = softplusf(su + gb[k]);
    w[t] = sigmoidf_(sw + ab[k]);
}

// ---------------------------------------------------------------------------
// Layer-0 fused message passing: M0[b,i,k*64+f] = sum_j A[b,k,i,j] * V[b,j,f]
// A computed on the fly from coords + u/w.  Tile: 16 i-rows x 64 j.
// ---------------------------------------------------------------------------
__global__ __launch_bounds__(256)
void msg0_kernel(const float* __restrict__ V, const float* __restrict__ C,
                 const float* __restrict__ u0, const float* __restrict__ w0,
                 float* __restrict__ M0) {
    const int N = 512, F = 64, TI = 16, TJ = 64;
    int b  = blockIdx.x >> 5;            // N/TI = 32 tiles per batch
    int i0 = (blockIdx.x & 31) * TI;
    int tid = threadIdx.x;

    __shared__ __align__(16) float s_v[TJ][F];       // 16 KB
    __shared__ float s_A[TI * KK][TJ + 1];           // 128x65 = 33.3 KB (pad: bank offset 8 between row-groups)
    __shared__ float s_d2[TI][TJ];                   // 4 KB
    __shared__ float s_cs[TI][TJ];                   // 4 KB
    __shared__ float s_cj[TJ][3];
    __shared__ float s_l2j[TJ];
    __shared__ float s_ci[TI][3];
    __shared__ float s_l2i[TI];
    __shared__ float s_u[TI][KK];
    __shared__ float s_w[TI][KK];

    if (tid < TI) {
        const float* cp = C + ((size_t)b * N + i0 + tid) * 3;
        float x = cp[0], y = cp[1], z = cp[2];
        s_ci[tid][0] = x; s_ci[tid][1] = y; s_ci[tid][2] = z;
        s_l2i[tid] = x * x + y * y + z * z;
    }
    if (tid < TI * KK) {
        int i = tid >> 3, k = tid & 7;
        size_t idx = ((size_t)b * N + i0 + i) * KK + k;
        s_u[i][k] = u0[idx];
        s_w[i][k] = w0[idx];
    }

    int f4 = tid & 15;    // 16 col-groups x float4 = 64 cols
    int rg = tid >> 4;    // 0..15 -> rows rg*8 .. rg*8+7
    float4 acc[8];
#pragma unroll
    for (int r = 0; r < 8; r++) acc[r] = make_float4(0.f, 0.f, 0.f, 0.f);

    for (int j0 = 0; j0 < N; j0 += TJ) {
        __syncthreads();
#pragma unroll
        for (int t = 0; t < (TJ * F) / 256; t++) {
            int idx = t * 256 + tid;
            int jj = idx >> 6, f = idx & 63;
            s_v[jj][f] = V[((size_t)b * N + j0 + jj) * F + f];
        }
        if (tid < TJ) {
            const float* cp = C + ((size_t)b * N + j0 + tid) * 3;
            float x = cp[0], y = cp[1], z = cp[2];
            s_cj[tid][0] = x; s_cj[tid][1] = y; s_cj[tid][2] = z;
            s_l2j[tid] = x * x + y * y + z * z;
        }
        __syncthreads();
#pragma unroll
        for (int t = 0; t < (TI * TJ) / 256; t++) {
            int p = t * 256 + tid;
            int i = p >> 6, j = p & 63;
            float dot = s_ci[i][0] * s_cj[j][0] + s_ci[i][1] * s_cj[j][1] + s_ci[i][2] * s_cj[j][2];
            float d2 = s_l2i[i] + s_l2j[j] - 2.f * dot;
            s_d2[i][j] = fabsf(d2) + EPSF;                       // = D^2 (sqrt then square cancels)
            s_cs[i][j] = dot / sqrtf((s_l2i[i] + EPSF) * (s_l2j[j] + EPSF));
        }
        __syncthreads();
#pragma unroll
        for (int t = 0; t < (TI * KK * TJ) / 256; t++) {
            int p = t * 256 + tid;
            int row = p >> 6, j = p & 63;
            int i = row >> 3, k = row & 7;
            float wk = s_w[i][k];
            s_A[row][j] = __expf(-s_d2[i][j] * s_u[i][k]) * (wk * s_cs[i][j] + 1.f - wk);
        }
        __syncthreads();
#pragma unroll 2
        for (int jj = 0; jj < TJ; jj++) {
            float4 v4 = *(const float4*)&s_v[jj][f4 * 4];
#pragma unroll
            for (int r = 0; r < 8; r++) {
                float a = s_A[rg * 8 + r][jj];
                acc[r].x += a * v4.x; acc[r].y += a * v4.y;
                acc[r].z += a * v4.z; acc[r].w += a * v4.w;
            }
        }
    }
#pragma unroll
    for (int r = 0; r < 8; r++) {
        int row = rg * 8 + r;
        int i = row >> 3, k = row & 7;
        *(float4*)&M0[((size_t)b * N + i0 + i) * 512 + k * 64 + f4 * 4] = acc[r];
    }
}

// ---------------------------------------------------------------------------
// Layer-1 fused message passing: M1[b,i,k*128+f] = sum_j A1[b,k,i,j]*H[b,j,f]
// Tile: 16 i-rows x 32 j, F=128.
// ---------------------------------------------------------------------------
__global__ __launch_bounds__(256)
void msg1_kernel(const float* __restrict__ H, const float* __restrict__ C1,
                 const float* __restrict__ u1, const float* __restrict__ w1,
                 float* __restrict__ M1) {
    const int N = 256, F = 128, TI = 16, TJ = 32;
    int b  = blockIdx.x >> 4;            // N/TI = 16 tiles per batch
    int i0 = (blockIdx.x & 15) * TI;
    int tid = threadIdx.x;

    __shared__ __align__(16) float s_h[TJ][F];       // 16 KB
    __shared__ float s_A[TI * KK][TJ + 1];           // 128x33 = 16.9 KB (bank offset 16 between row-groups)
    __shared__ float s_d2[TI][TJ];
    __shared__ float s_cs[TI][TJ];
    __shared__ float s_cj[TJ][3];
    __shared__ float s_l2j[TJ];
    __shared__ float s_ci[TI][3];
    __shared__ float s_l2i[TI];
    __shared__ float s_u[TI][KK];
    __shared__ float s_w[TI][KK];

    if (tid < TI) {
        const float* cp = C1 + ((size_t)b * N + i0 + tid) * 3;
        float x = cp[0], y = cp[1], z = cp[2];
        s_ci[tid][0] = x; s_ci[tid][1] = y; s_ci[tid][2] = z;
        s_l2i[tid] = x * x + y * y + z * z;
    }
    if (tid < TI * KK) {
        int i = tid >> 3, k = tid & 7;
        size_t idx = ((size_t)b * N + i0 + i) * KK + k;
        s_u[i][k] = u1[idx];
        s_w[i][k] = w1[idx];
    }

    int f4 = tid & 31;    // 32 col-groups x float4 = 128 cols
    int rg = tid >> 5;    // 0..7 -> rows rg*16 .. rg*16+15
    float4 acc[16];
#pragma unroll
    for (int r = 0; r < 16; r++) acc[r] = make_float4(0.f, 0.f, 0.f, 0.f);

    for (int j0 = 0; j0 < N; j0 += TJ) {
        __syncthreads();
#pragma unroll
        for (int t = 0; t < (TJ * F) / 256; t++) {
            int idx = t * 256 + tid;
            int jj = idx >> 7, f = idx & 127;
            s_h[jj][f] = H[((size_t)b * N + j0 + jj) * F + f];
        }
        if (tid < TJ) {
            const float* cp = C1 + ((size_t)b * N + j0 + tid) * 3;
            float x = cp[0], y = cp[1], z = cp[2];
            s_cj[tid][0] = x; s_cj[tid][1] = y; s_cj[tid][2] = z;
            s_l2j[tid] = x * x + y * y + z * z;
        }
        __syncthreads();
#pragma unroll
        for (int t = 0; t < (TI * TJ) / 256; t++) {
            int p = t * 256 + tid;
            int i = p >> 5, j = p & 31;
            float dot = s_ci[i][0] * s_cj[j][0] + s_ci[i][1] * s_cj[j][1] + s_ci[i][2] * s_cj[j][2];
            float d2 = s_l2i[i] + s_l2j[j] - 2.f * dot;
            s_d2[i][j] = fabsf(d2) + EPSF;
            s_cs[i][j] = dot / sqrtf((s_l2i[i] + EPSF) * (s_l2j[j] + EPSF));
        }
        __syncthreads();
#pragma unroll
        for (int t = 0; t < (TI * KK * TJ) / 256; t++) {
            int p = t * 256 + tid;
            int row = p >> 5, j = p & 31;
            int i = row >> 3, k = row & 7;
            float wk = s_w[i][k];
            s_A[row][j] = __expf(-s_d2[i][j] * s_u[i][k]) * (wk * s_cs[i][j] + 1.f - wk);
        }
        __syncthreads();
#pragma unroll 2
        for (int jj = 0; jj < TJ; jj++) {
            float4 h4 = *(const float4*)&s_h[jj][f4 * 4];
#pragma unroll
            for (int r = 0; r < 16; r++) {
                float a = s_A[rg * 16 + r][jj];
                acc[r].x += a * h4.x; acc[r].y += a * h4.y;
                acc[r].z += a * h4.z; acc[r].w += a * h4.w;
            }
        }
    }
#pragma unroll
    for (int r = 0; r < 16; r++) {
        int row = rg * 16 + r;
        int i = row >> 3, k = row & 7;
        *(float4*)&M1[((size_t)b * N + i0 + i) * 1024 + k * 128 + f4 * 4] = acc[r];
    }
}

// ---------------------------------------------------------------------------
// post0: H = bn_g*tanh([V|M0] @ W + b) + bn_b, then pool pairs -> H0p [B*256,128]
// 32 rows/block, inner 576 = 9 chunks of 64, 128 cols.
// ---------------------------------------------------------------------------
__global__ __launch_bounds__(256)
void post0_kernel(const float* __restrict__ V, const float* __restrict__ M0,
                  const float* __restrict__ W, const float* __restrict__ bias,
                  const float* __restrict__ bng, const float* __restrict__ bnb,
                  float* __restrict__ Hp) {
    const int TI = 32, CH = 64, FOUT = 128;
    int row0 = blockIdx.x * TI;          // flattened [B*512] row base
    int tid = threadIdx.x;
    __shared__ __align__(16) float s_W[CH][FOUT];    // 32 KB
    __shared__ float s_X[TI][CH + 1];                // 8.3 KB

    int c4 = tid & 31;   // cols 4*c4 .. +3
    int g  = tid >> 5;   // 0..7 -> rows g*4 .. +3
    float4 acc[4];
#pragma unroll
    for (int r = 0; r < 4; r++) acc[r] = make_float4(0.f, 0.f, 0.f, 0.f);

    for (int ic = 0; ic < 9; ic++) {
        __syncthreads();
#pragma unroll
        for (int t = 0; t < 32; t++) {
            int idx = t * 256 + tid;
            int jj = idx >> 7, c = idx & 127;
            s_W[jj][c] = W[((size_t)ic * 64 + jj) * FOUT + c];
        }
#pragma unroll
        for (int t = 0; t < 8; t++) {
            int idx = t * 256 + tid;
            int r = idx >> 6, j = idx & 63;
            float x;
            if (ic == 0) x = V[((size_t)row0 + r) * 64 + j];
            else         x = M0[((size_t)row0 + r) * 512 + (ic - 1) * 64 + j];
            s_X[r][j] = x;
        }
        __syncthreads();
#pragma unroll 2
        for (int jj = 0; jj < CH; jj++) {
            float4 w4 = *(const float4*)&s_W[jj][c4 * 4];
#pragma unroll
            for (int r = 0; r < 4; r++) {
                float x = s_X[g * 4 + r][jj];
                acc[r].x += x * w4.x; acc[r].y += x * w4.y;
                acc[r].z += x * w4.z; acc[r].w += x * w4.w;
            }
        }
    }
    float4 bs = *(const float4*)&bias[c4 * 4];
    float4 gg = *(const float4*)&bng[c4 * 4];
    float4 bb = *(const float4*)&bnb[c4 * 4];
    float h[4][4];
#pragma unroll
    for (int r = 0; r < 4; r++) {
        h[r][0] = gg.x * tanhf(acc[r].x + bs.x) + bb.x;
        h[r][1] = gg.y * tanhf(acc[r].y + bs.y) + bb.y;
        h[r][2] = gg.z * tanhf(acc[r].z + bs.z) + bb.z;
        h[r][3] = gg.w * tanhf(acc[r].w + bs.w) + bb.w;
    }
#pragma unroll
    for (int q = 0; q < 2; q++) {
        float4 o;
        o.x = 0.5f * (h[2 * q][0] + h[2 * q + 1][0]);
        o.y = 0.5f * (h[2 * q][1] + h[2 * q + 1][1]);
        o.z = 0.5f * (h[2 * q][2] + h[2 * q + 1][2]);
        o.w = 0.5f * (h[2 * q][3] + h[2 * q + 1][3]);
        size_t prow = (size_t)(row0 >> 1) + g * 2 + q;
        *(float4*)&Hp[prow * FOUT + c4 * 4] = o;
    }
}

// ---------------------------------------------------------------------------
// post1: H1 = bn_g*tanh([H0p|M1] @ W + b) + bn_b, pool pairs -> H1p [B*128,256]
// 16 rows/block, inner 1152 = 36 chunks of 32, 256 cols.
// ---------------------------------------------------------------------------
__global__ __launch_bounds__(256)
void post1_kernel(const float* __restrict__ H, const float* __restrict__ M1,
                  const float* __restrict__ W, const float* __restrict__ bias,
                  const float* __restrict__ bng, const float* __restrict__ bnb,
                  float* __restrict__ Hp) {
    const int TI = 16, CH = 32, FOUT = 256;
    int row0 = blockIdx.x * TI;          // flattened [B*256] row base
    int tid = threadIdx.x;
    __shared__ __align__(16) float s_W[CH][FOUT];    // 32 KB
    __shared__ float s_X[TI][CH + 1];                // 2.1 KB

    int c4 = tid & 63;   // cols 4*c4 .. +3  (256 cols)
    int g  = tid >> 6;   // 0..3 -> rows g*4 .. +3
    float4 acc[4];
#pragma unroll
    for (int r = 0; r < 4; r++) acc[r] = make_float4(0.f, 0.f, 0.f, 0.f);

    for (int ic = 0; ic < 36; ic++) {
        __syncthreads();
#pragma unroll
        for (int t = 0; t < 32; t++) {
            int idx = t * 256 + tid;
            int jj = idx >> 8, c = idx & 255;
            s_W[jj][c] = W[((size_t)ic * 32 + jj) * FOUT + c];
        }
#pragma unroll
        for (int t = 0; t < 2; t++) {
            int idx = t * 256 + tid;
            int r = idx >> 5, j = idx & 31;
            float x;
            if (ic < 4) x = H[((size_t)row0 + r) * 128 + ic * 32 + j];
            else        x = M1[((size_t)row0 + r) * 1024 + (ic - 4) * 32 + j];
            s_X[r][j] = x;
        }
        __syncthreads();
#pragma unroll 2
        for (int jj = 0; jj < CH; jj++) {
            float4 w4 = *(const float4*)&s_W[jj][c4 * 4];
#pragma unroll
            for (int r = 0; r < 4; r++) {
                float x = s_X[g * 4 + r][jj];
                acc[r].x += x * w4.x; acc[r].y += x * w4.y;
                acc[r].z += x * w4.z; acc[r].w += x * w4.w;
            }
        }
    }
    float4 bs = *(const float4*)&bias[c4 * 4];
    float4 gg = *(const float4*)&bng[c4 * 4];
    float4 bb = *(const float4*)&bnb[c4 * 4];
    float h[4][4];
#pragma unroll
    for (int r = 0; r < 4; r++) {
        h[r][0] = gg.x * tanhf(acc[r].x + bs.x) + bb.x;
        h[r][1] = gg.y * tanhf(acc[r].y + bs.y) + bb.y;
        h[r][2] = gg.z * tanhf(acc[r].z + bs.z) + bb.z;
        h[r][3] = gg.w * tanhf(acc[r].w + bs.w) + bb.w;
    }
#pragma unroll
    for (int q = 0; q < 2; q++) {
        float4 o;
        o.x = 0.5f * (h[2 * q][0] + h[2 * q + 1][0]);
        o.y = 0.5f * (h[2 * q][1] + h[2 * q + 1][1]);
        o.z = 0.5f * (h[2 * q][2] + h[2 * q + 1][2]);
        o.w = 0.5f * (h[2 * q][3] + h[2 * q + 1][3]);
        size_t prow = (size_t)(row0 >> 1) + g * 2 + q;
        *(float4*)&Hp[prow * FOUT + c4 * 4] = o;
    }
}

// ---------------------------------------------------------------------------
// Pool coords: C1[b,i,:] = 0.5*(C[b,2i,:] + C[b,2i+1,:])
// ---------------------------------------------------------------------------
__global__ void c1pool_kernel(const float* __restrict__ C, float* __restrict__ C1) {
    int o = blockIdx.x * 256 + threadIdx.x;
    if (o >= 16 * 256 * 3) return;
    int d = o % 3;
    int node = o / 3;
    int b = node >> 8, i = node & 255;
    size_t src = ((size_t)(b * 512 + 2 * i)) * 3 + d;
    C1[o] = 0.5f * (C[src] + C[src + 3]);
}

// ---------------------------------------------------------------------------
// FC split-K: P[ks,b,o] = sum_{m in chunk} Flat[b,m] * fc_w[m,o]
// grid 256 = 8 o-splits x 32 k-splits; each block 16 rows x 64 cols x 1024 m.
// ---------------------------------------------------------------------------
__global__ __launch_bounds__(256)
void fc_partial_kernel(const float* __restrict__ Flat, const float* __restrict__ W,
                       float* __restrict__ P) {
    int os = blockIdx.x & 7, ks = blockIdx.x >> 3;
    int o0 = os * 64;
    int m0 = ks * 1024;
    int r = threadIdx.x >> 4, c4 = threadIdx.x & 15;
    const float* fr = Flat + (size_t)r * 32768;
    float4 acc = make_float4(0.f, 0.f, 0.f, 0.f);
#pragma unroll 8
    for (int m = m0; m < m0 + 1024; m++) {
        float4 w4 = *(const float4*)&W[(size_t)m * 512 + o0 + c4 * 4];
        float x = fr[m];
        acc.x += x * w4.x; acc.y += x * w4.y;
        acc.z += x * w4.z; acc.w += x * w4.w;
    }
    *(float4*)&P[((size_t)ks * 16 + r) * 512 + o0 + c4 * 4] = acc;
}

__global__ void fc_reduce_kernel(const float* __restrict__ P, const float* __restrict__ fcb,
                                 float* __restrict__ out) {
    int idx = blockIdx.x * 256 + threadIdx.x;   // 8192 outputs
    float s = fcb[idx & 511];
    for (int ks = 0; ks < 32; ks++) s += P[(size_t)ks * 8192 + idx];
    out[idx] = 1.f / (1.f + expf(-s));
}

// ---------------------------------------------------------------------------
extern "C" void kernel_launch(void* const* d_in, const int* in_sizes, int n_in,
                              void* d_out, int out_size, void* d_ws, size_t ws_size,
                              hipStream_t stream) {
    const float* V     = (const float*)d_in[0];
    const float* C     = (const float*)d_in[1];
    const float* gk_w0 = (const float*)d_in[2];
    const float* gk_b0 = (const float*)d_in[3];
    const float* ac_w0 = (const float*)d_in[4];
    const float* ac_b0 = (const float*)d_in[5];
    const float* gc_w0 = (const float*)d_in[6];
    const float* gc_b0 = (const float*)d_in[7];
    const float* bn_g0 = (const float*)d_in[8];
    const float* bn_b0 = (const float*)d_in[9];
    const float* gk_w1 = (const float*)d_in[10];
    const float* gk_b1 = (const float*)d_in[11];
    const float* ac_w1 = (const float*)d_in[12];
    const float* ac_b1 = (const float*)d_in[13];
    const float* gc_w1 = (const float*)d_in[14];
    const float* gc_b1 = (const float*)d_in[15];
    const float* bn_g1 = (const float*)d_in[16];
    const float* bn_b1 = (const float*)d_in[17];
    const float* fc_w  = (const float*)d_in[18];
    const float* fc_b  = (const float*)d_in[19];
    float* out = (float*)d_out;
    float* ws  = (float*)d_ws;

    // workspace layout (floats); M buffer reused for M0 then M1 (strict stream order)
    float* u0  = ws;                  // 65536
    float* w0  = u0 + 65536;          // 65536
    float* M   = w0 + 65536;          // 4194304
    float* H0p = M + 4194304;         // 524288
    float* C1  = H0p + 524288;        // 12288
    float* u1  = C1 + 12288;          // 32768
    float* w1  = u1 + 32768;          // 32768
    float* H1p = w1 + 32768;          // 524288
    float* P   = H1p + 524288;        // 262144
    // total 5,713,920 floats = 21.8 MiB

    uw_kernel<<<256, 256, 0, stream>>>(V, gk_w0, gk_b0, ac_w0, ac_b0, u0, w0, 8192, 64);
    msg0_kernel<<<512, 256, 0, stream>>>(V, C, u0, w0, M);
    post0_kernel<<<256, 256, 0, stream>>>(V, M, gc_w0, gc_b0, bn_g0, bn_b0, H0p);
    c1pool_kernel<<<48, 256, 0, stream>>>(C, C1);
    uw_kernel<<<128, 256, 0, stream>>>(H0p, gk_w1, gk_b1, ac_w1, ac_b1, u1, w1, 4096, 128);
    msg1_kernel<<<256, 256, 0, stream>>>(H0p, C1, u1, w1, M);
    post1_kernel<<<256, 256, 0, stream>>>(H0p, M, gc_w1, gc_b1, bn_g1, bn_b1, H1p);
    fc_partial_kernel<<<256, 256, 0, stream>>>(H1p, fc_w, P);
    fc_reduce_kernel<<<32, 256, 0, stream>>>(P, fc_b, out);
}

// Round 2
// 456.006 us; speedup vs baseline: 1.3089x; 1.3089x over previous
//
#include <hip/hip_runtime.h>
#include <math.h>

#define KK 8
#define EPSF 1e-9f

typedef unsigned int   uint32;
typedef unsigned short ushort16;
typedef __attribute__((ext_vector_type(8))) short bf16x8;
typedef __attribute__((ext_vector_type(4))) float f32x4;

#define MFMA_16x16x32(a, b, c) __builtin_amdgcn_mfma_f32_16x16x32_bf16(a, b, c, 0, 0, 0)

__device__ __forceinline__ float softplusf(float x) {
    return x > 0.0f ? x + log1pf(expf(-x)) : log1pf(expf(x));
}
__device__ __forceinline__ float sigmoidf_(float x) {
    return 1.0f / (1.0f + expf(-x));
}
// fp32 -> bf16 round-to-nearest-even
__device__ __forceinline__ ushort16 f2bf(float f) {
    union { float f; uint32 u; } v; v.f = f;
    uint32 u = v.u;
    return (ushort16)((u + 0x7FFFu + ((u >> 16) & 1u)) >> 16);
}

// ---------------------------------------------------------------------------
// prep: V->VT0 bf16 [16][64][512] (transposed), gc_w0->Wt0 bf16 [128][576],
//       gc_w1->Wt1 bf16 [256][1152], V->X0[:, :64] bf16 (straight).
// ---------------------------------------------------------------------------
__global__ __launch_bounds__(256)
void prep_kernel(const float* __restrict__ V, const float* __restrict__ W0,
                 const float* __restrict__ W1, ushort16* __restrict__ VT0,
                 ushort16* __restrict__ Wt0, ushort16* __restrict__ Wt1,
                 ushort16* __restrict__ X0) {
    __shared__ float s[64][65];
    int blk = blockIdx.x, tid = threadIdx.x;
    if (blk < 128) {            // V [16][512][64] -> VT0 [16][64][512]
        int b = blk >> 3, rt = blk & 7;
#pragma unroll
        for (int t = 0; t < 16; t++) {
            int idx = t * 256 + tid; int r = idx >> 6, c = idx & 63;
            s[r][c] = V[((size_t)b * 512 + rt * 64 + r) * 64 + c];
        }
        __syncthreads();
#pragma unroll
        for (int t = 0; t < 16; t++) {
            int idx = t * 256 + tid; int f = idx >> 6, j = idx & 63;
            VT0[((size_t)b * 64 + f) * 512 + rt * 64 + j] = f2bf(s[j][f]);
        }
    } else if (blk < 146) {     // W0 [576][128] -> Wt0 [128][576]
        int t0 = blk - 128; int rt = t0 >> 1, ct = t0 & 1;
#pragma unroll
        for (int t = 0; t < 16; t++) {
            int idx = t * 256 + tid; int r = idx >> 6, c = idx & 63;
            s[r][c] = W0[((size_t)rt * 64 + r) * 128 + ct * 64 + c];
        }
        __syncthreads();
#pragma unroll
        for (int t = 0; t < 16; t++) {
            int idx = t * 256 + tid; int f = idx >> 6, j = idx & 63;
            Wt0[((size_t)ct * 64 + f) * 576 + rt * 64 + j] = f2bf(s[j][f]);
        }
    } else if (blk < 218) {     // W1 [1152][256] -> Wt1 [256][1152]
        int t0 = blk - 146; int rt = t0 >> 2, ct = t0 & 3;
#pragma unroll
        for (int t = 0; t < 16; t++) {
            int idx = t * 256 + tid; int r = idx >> 6, c = idx & 63;
            s[r][c] = W1[((size_t)rt * 64 + r) * 256 + ct * 64 + c];
        }
        __syncthreads();
#pragma unroll
        for (int t = 0; t < 16; t++) {
            int idx = t * 256 + tid; int f = idx >> 6, j = idx & 63;
            Wt1[((size_t)ct * 64 + f) * 1152 + rt * 64 + j] = f2bf(s[j][f]);
        }
    } else {                    // V flat -> X0[:, 0:64] bf16 (128 blocks x 4096 elems)
        int t0 = blk - 218;
#pragma unroll
        for (int q = 0; q < 16; q++) {
            int e = t0 * 4096 + q * 256 + tid;           // e < 524288 exactly
            int row = e >> 6, c = e & 63;
            X0[(size_t)row * 576 + c] = f2bf(V[e]);
        }
    }
}

// ---------------------------------------------------------------------------
// transpose H0p [16][256][128] fp32 -> VT1 [16][128][256] bf16
// ---------------------------------------------------------------------------
__global__ __launch_bounds__(256)
void t_h0p_kernel(const float* __restrict__ H0p, ushort16* __restrict__ VT1) {
    __shared__ float s[64][65];
    int blk = blockIdx.x, tid = threadIdx.x;
    int b = blk >> 3, rt = (blk >> 1) & 3, ct = blk & 1;
#pragma unroll
    for (int t = 0; t < 16; t++) {
        int idx = t * 256 + tid; int r = idx >> 6, c = idx & 63;
        s[r][c] = H0p[((size_t)b * 256 + rt * 64 + r) * 128 + ct * 64 + c];
    }
    __syncthreads();
#pragma unroll
    for (int t = 0; t < 16; t++) {
        int idx = t * 256 + tid; int f = idx >> 6, j = idx & 63;
        VT1[((size_t)b * 128 + ct * 64 + f) * 256 + rt * 64 + j] = f2bf(s[j][f]);
    }
}

// ---------------------------------------------------------------------------
// u = softplus(X @ gw + gb), w = sigmoid(X @ aw + ab), per (row, k)
// ---------------------------------------------------------------------------
__global__ __launch_bounds__(256)
void uw_kernel(const float* __restrict__ X, const float* __restrict__ gw,
               const float* __restrict__ gb, const float* __restrict__ aw,
               const float* __restrict__ ab, float* __restrict__ u,
               float* __restrict__ w, int rows, int F) {
    int t = blockIdx.x * 256 + threadIdx.x;
    if (t >= rows * KK) return;
    int row = t >> 3, k = t & 7;
    const float* xr = X + (size_t)row * F;
    float su = 0.f, sw = 0.f;
    for (int f = 0; f < F; f++) {
        float x = xr[f];
        su += x * gw[f * KK + k];
        sw += x * aw[f * KK + k];
    }
    u[t] = softplusf(su + gb[k]);
    w[t] = sigmoidf_(sw + ab[k]);
}

// ---------------------------------------------------------------------------
// msg0 MFMA: M0-tile = A(128 ik x 512 j) * V(512 j x 64 f), bf16 mfma.
// Writes M0 bf16 into X0[:, 64:576]. Grid 512 = 16 b x 32 i-tiles.
// ---------------------------------------------------------------------------
__global__ __launch_bounds__(256)
void msg0_mfma(const ushort16* __restrict__ VT0, const float* __restrict__ C,
               const float* __restrict__ u0, const float* __restrict__ w0,
               ushort16* __restrict__ X0) {
    const int TI = 16;
    int b = blockIdx.x >> 5, i0 = (blockIdx.x & 31) * TI;
    int tid = threadIdx.x;
    int wv = tid >> 6, lane = tid & 63, quad = lane >> 4, l15 = lane & 15;

    __shared__ __align__(16) ushort16 s_vT[64][72];   // [f][j], stride 144 B
    __shared__ __align__(16) ushort16 s_A[128][72];   // [ik][j]
    __shared__ float s_d2[16][64];
    __shared__ float s_cs[16][64];
    __shared__ float s_cj[64][3];
    __shared__ float s_l2j[64];
    __shared__ float s_ci[16][3];
    __shared__ float s_l2i[16];
    __shared__ float s_u[16][KK];
    __shared__ float s_w[16][KK];

    if (tid < 16) {
        const float* cp = C + ((size_t)b * 512 + i0 + tid) * 3;
        float x = cp[0], y = cp[1], z = cp[2];
        s_ci[tid][0] = x; s_ci[tid][1] = y; s_ci[tid][2] = z;
        s_l2i[tid] = x * x + y * y + z * z;
    }
    if (tid < 128) {
        int i = tid >> 3, k = tid & 7;
        size_t idx = ((size_t)b * 512 + i0 + i) * KK + k;
        s_u[i][k] = u0[idx];
        s_w[i][k] = w0[idx];
    }

    f32x4 acc[2][4] = {};

    for (int j0 = 0; j0 < 512; j0 += 64) {
        __syncthreads();
#pragma unroll
        for (int t = 0; t < 8; t++) {       // stage V^T tile (2048 dwords)
            int idx = t * 256 + tid; int f = idx >> 5, j2 = idx & 31;
            *(uint32*)&s_vT[f][j2 * 2] =
                *(const uint32*)&VT0[((size_t)b * 64 + f) * 512 + j0 + j2 * 2];
        }
        if (tid < 64) {
            const float* cp = C + ((size_t)b * 512 + j0 + tid) * 3;
            float x = cp[0], y = cp[1], z = cp[2];
            s_cj[tid][0] = x; s_cj[tid][1] = y; s_cj[tid][2] = z;
            s_l2j[tid] = x * x + y * y + z * z;
        }
        __syncthreads();
#pragma unroll
        for (int t = 0; t < 4; t++) {       // d2 / cos (1024 pairs)
            int p = t * 256 + tid; int i = p >> 6, j = p & 63;
            float dot = s_ci[i][0] * s_cj[j][0] + s_ci[i][1] * s_cj[j][1] + s_ci[i][2] * s_cj[j][2];
            float d2 = s_l2i[i] + s_l2j[j] - 2.f * dot;
            s_d2[i][j] = fabsf(d2) + EPSF;
            s_cs[i][j] = dot / sqrtf((s_l2i[i] + EPSF) * (s_l2j[j] + EPSF));
        }
        __syncthreads();
#pragma unroll
        for (int t = 0; t < 16; t++) {      // A bf16 (4096 pairs of j)
            int p = t * 256 + tid; int row = p >> 5, j2 = p & 31;
            int i = row >> 3, k = row & 7;
            float uu = s_u[i][k], ww = s_w[i][k];
            float a0 = __expf(-s_d2[i][2 * j2]     * uu) * (ww * s_cs[i][2 * j2]     + 1.f - ww);
            float a1 = __expf(-s_d2[i][2 * j2 + 1] * uu) * (ww * s_cs[i][2 * j2 + 1] + 1.f - ww);
            *(uint32*)&s_A[row][2 * j2] = (uint32)f2bf(a0) | ((uint32)f2bf(a1) << 16);
        }
        __syncthreads();
#pragma unroll
        for (int ks = 0; ks < 2; ks++) {
            int kk = ks * 32 + quad * 8;
            bf16x8 a0 = *(const bf16x8*)&s_A[wv * 32 + l15][kk];
            bf16x8 a1 = *(const bf16x8*)&s_A[wv * 32 + 16 + l15][kk];
#pragma unroll
            for (int cf = 0; cf < 4; cf++) {
                bf16x8 bv = *(const bf16x8*)&s_vT[cf * 16 + l15][kk];
                acc[0][cf] = MFMA_16x16x32(a0, bv, acc[0][cf]);
                acc[1][cf] = MFMA_16x16x32(a1, bv, acc[1][cf]);
            }
        }
    }
#pragma unroll
    for (int rf = 0; rf < 2; rf++)
#pragma unroll
        for (int cf = 0; cf < 4; cf++)
#pragma unroll
            for (int r = 0; r < 4; r++) {
                int arow = wv * 32 + rf * 16 + quad * 4 + r;
                int i = arow >> 3, k = arow & 7;
                X0[((size_t)b * 512 + i0 + i) * 576 + 64 + k * 64 + cf * 16 + l15] =
                    f2bf(acc[rf][cf][r]);
            }
}

// ---------------------------------------------------------------------------
// msg1 MFMA: A(128 ik x 256 j) * H(256 j x 128 f). Writes X1[:, 128:1152].
// Grid 256 = 16 b x 16 i-tiles.
// ---------------------------------------------------------------------------
__global__ __launch_bounds__(256)
void msg1_mfma(const ushort16* __restrict__ VT1, const float* __restrict__ C1,
               const float* __restrict__ u1, const float* __restrict__ w1,
               ushort16* __restrict__ X1) {
    const int TI = 16;
    int b = blockIdx.x >> 4, i0 = (blockIdx.x & 15) * TI;
    int tid = threadIdx.x;
    int wv = tid >> 6, lane = tid & 63, quad = lane >> 4, l15 = lane & 15;

    __shared__ __align__(16) ushort16 s_vT[128][72];
    __shared__ __align__(16) ushort16 s_A[128][72];
    __shared__ float s_d2[16][64];
    __shared__ float s_cs[16][64];
    __shared__ float s_cj[64][3];
    __shared__ float s_l2j[64];
    __shared__ float s_ci[16][3];
    __shared__ float s_l2i[16];
    __shared__ float s_u[16][KK];
    __shared__ float s_w[16][KK];

    if (tid < 16) {
        const float* cp = C1 + ((size_t)b * 256 + i0 + tid) * 3;
        float x = cp[0], y = cp[1], z = cp[2];
        s_ci[tid][0] = x; s_ci[tid][1] = y; s_ci[tid][2] = z;
        s_l2i[tid] = x * x + y * y + z * z;
    }
    if (tid < 128) {
        int i = tid >> 3, k = tid & 7;
        size_t idx = ((size_t)b * 256 + i0 + i) * KK + k;
        s_u[i][k] = u1[idx];
        s_w[i][k] = w1[idx];
    }

    f32x4 acc[2][8] = {};

    for (int j0 = 0; j0 < 256; j0 += 64) {
        __syncthreads();
#pragma unroll
        for (int t = 0; t < 16; t++) {      // stage H^T tile: 128 f x 64 j (4096 dwords)
            int idx = t * 256 + tid; int f = idx >> 5, j2 = idx & 31;
            *(uint32*)&s_vT[f][j2 * 2] =
                *(const uint32*)&VT1[((size_t)b * 128 + f) * 256 + j0 + j2 * 2];
        }
        if (tid < 64) {
            const float* cp = C1 + ((size_t)b * 256 + j0 + tid) * 3;
            float x = cp[0], y = cp[1], z = cp[2];
            s_cj[tid][0] = x; s_cj[tid][1] = y; s_cj[tid][2] = z;
            s_l2j[tid] = x * x + y * y + z * z;
        }
        __syncthreads();
#pragma unroll
        for (int t = 0; t < 4; t++) {
            int p = t * 256 + tid; int i = p >> 6, j = p & 63;
            float dot = s_ci[i][0] * s_cj[j][0] + s_ci[i][1] * s_cj[j][1] + s_ci[i][2] * s_cj[j][2];
            float d2 = s_l2i[i] + s_l2j[j] - 2.f * dot;
            s_d2[i][j] = fabsf(d2) + EPSF;
            s_cs[i][j] = dot / sqrtf((s_l2i[i] + EPSF) * (s_l2j[j] + EPSF));
        }
        __syncthreads();
#pragma unroll
        for (int t = 0; t < 16; t++) {
            int p = t * 256 + tid; int row = p >> 5, j2 = p & 31;
            int i = row >> 3, k = row & 7;
            float uu = s_u[i][k], ww = s_w[i][k];
            float a0 = __expf(-s_d2[i][2 * j2]     * uu) * (ww * s_cs[i][2 * j2]     + 1.f - ww);
            float a1 = __expf(-s_d2[i][2 * j2 + 1] * uu) * (ww * s_cs[i][2 * j2 + 1] + 1.f - ww);
            *(uint32*)&s_A[row][2 * j2] = (uint32)f2bf(a0) | ((uint32)f2bf(a1) << 16);
        }
        __syncthreads();
#pragma unroll
        for (int ks = 0; ks < 2; ks++) {
            int kk = ks * 32 + quad * 8;
            bf16x8 a0 = *(const bf16x8*)&s_A[wv * 32 + l15][kk];
            bf16x8 a1 = *(const bf16x8*)&s_A[wv * 32 + 16 + l15][kk];
#pragma unroll
            for (int cf = 0; cf < 8; cf++) {
                bf16x8 bv = *(const bf16x8*)&s_vT[cf * 16 + l15][kk];
                acc[0][cf] = MFMA_16x16x32(a0, bv, acc[0][cf]);
                acc[1][cf] = MFMA_16x16x32(a1, bv, acc[1][cf]);
            }
        }
    }
#pragma unroll
    for (int rf = 0; rf < 2; rf++)
#pragma unroll
        for (int cf = 0; cf < 8; cf++)
#pragma unroll
            for (int r = 0; r < 4; r++) {
                int arow = wv * 32 + rf * 16 + quad * 4 + r;
                int i = arow >> 3, k = arow & 7;
                X1[((size_t)b * 256 + i0 + i) * 1152 + 128 + k * 128 + cf * 16 + l15] =
                    f2bf(acc[rf][cf][r]);
            }
}

// ---------------------------------------------------------------------------
// post0 MFMA GEMM: [8192 x 576] @ [576 x 128] -> tanh/bn -> pool ->
// H0p fp32 [4096][128] + X1[:, :128] bf16. Grid 256, block tile 32x128.
// ---------------------------------------------------------------------------
__global__ __launch_bounds__(256)
void post0_mfma(const ushort16* __restrict__ X0, const ushort16* __restrict__ Wt,
                const float* __restrict__ bias, const float* __restrict__ bng,
                const float* __restrict__ bnb, float* __restrict__ H0p,
                ushort16* __restrict__ X1) {
    int row0 = blockIdx.x * 32;
    int tid = threadIdx.x;
    int wv = tid >> 6, lane = tid & 63, quad = lane >> 4, l15 = lane & 15;
    int rw = wv & 1, cw = wv >> 1;

    __shared__ __align__(16) ushort16 s_X[32][72];
    __shared__ __align__(16) ushort16 s_W[128][72];

    f32x4 acc[4] = {};

    for (int kc = 0; kc < 576; kc += 64) {
        __syncthreads();
#pragma unroll
        for (int t = 0; t < 4; t++) {       // 1024 dwords
            int p = t * 256 + tid; int r = p >> 5, k2 = p & 31;
            *(uint32*)&s_X[r][k2 * 2] =
                *(const uint32*)&X0[((size_t)row0 + r) * 576 + kc + k2 * 2];
        }
#pragma unroll
        for (int t = 0; t < 16; t++) {      // 4096 dwords
            int p = t * 256 + tid; int c = p >> 5, k2 = p & 31;
            *(uint32*)&s_W[c][k2 * 2] =
                *(const uint32*)&Wt[(size_t)c * 576 + kc + k2 * 2];
        }
        __syncthreads();
#pragma unroll
        for (int ks = 0; ks < 2; ks++) {
            int kk = ks * 32 + quad * 8;
            bf16x8 av = *(const bf16x8*)&s_X[rw * 16 + l15][kk];
#pragma unroll
            for (int cf = 0; cf < 4; cf++) {
                bf16x8 bv = *(const bf16x8*)&s_W[cw * 64 + cf * 16 + l15][kk];
                acc[cf] = MFMA_16x16x32(av, bv, acc[cf]);
            }
        }
    }
#pragma unroll
    for (int cf = 0; cf < 4; cf++) {
        int col = cw * 64 + cf * 16 + l15;
        float bs = bias[col], gg = bng[col], bb = bnb[col];
        float h0 = gg * tanhf(acc[cf][0] + bs) + bb;
        float h1 = gg * tanhf(acc[cf][1] + bs) + bb;
        float h2 = gg * tanhf(acc[cf][2] + bs) + bb;
        float h3 = gg * tanhf(acc[cf][3] + bs) + bb;
        float p0 = 0.5f * (h0 + h1), p1 = 0.5f * (h2 + h3);
        size_t pr = (size_t)(row0 >> 1) + rw * 8 + quad * 2;
        H0p[pr * 128 + col] = p0;
        H0p[(pr + 1) * 128 + col] = p1;
        X1[pr * 1152 + col] = f2bf(p0);
        X1[(pr + 1) * 1152 + col] = f2bf(p1);
    }
}

// ---------------------------------------------------------------------------
// post1 MFMA GEMM: [4096 x 1152] @ [1152 x 256] -> tanh/bn -> pool ->
// H1p fp32 [2048][256]. Grid 256, block tile 16x256.
// ---------------------------------------------------------------------------
__global__ __launch_bounds__(256)
void post1_mfma(const ushort16* __restrict__ X1, const ushort16* __restrict__ Wt,
                const float* __restrict__ bias, const float* __restrict__ bng,
                const float* __restrict__ bnb, float* __restrict__ H1p) {
    int row0 = blockIdx.x * 16;
    int tid = threadIdx.x;
    int wv = tid >> 6, lane = tid & 63, quad = lane >> 4, l15 = lane & 15;

    __shared__ __align__(16) ushort16 s_X[16][72];
    __shared__ __align__(16) ushort16 s_W[256][72];

    f32x4 acc[4] = {};

    for (int kc = 0; kc < 1152; kc += 64) {
        __syncthreads();
#pragma unroll
        for (int t = 0; t < 2; t++) {       // 512 dwords
            int p = t * 256 + tid; int r = p >> 5, k2 = p & 31;
            *(uint32*)&s_X[r][k2 * 2] =
                *(const uint32*)&X1[((size_t)row0 + r) * 1152 + kc + k2 * 2];
        }
#pragma unroll
        for (int t = 0; t < 32; t++) {      // 8192 dwords
            int p = t * 256 + tid; int c = p >> 5, k2 = p & 31;
            *(uint32*)&s_W[c][k2 * 2] =
                *(const uint32*)&Wt[(size_t)c * 1152 + kc + k2 * 2];
        }
        __syncthreads();
#pragma unroll
        for (int ks = 0; ks < 2; ks++) {
            int kk = ks * 32 + quad * 8;
            bf16x8 av = *(const bf16x8*)&s_X[l15][kk];
#pragma unroll
            for (int cf = 0; cf < 4; cf++) {
                bf16x8 bv = *(const bf16x8*)&s_W[wv * 64 + cf * 16 + l15][kk];
                acc[cf] = MFMA_16x16x32(av, bv, acc[cf]);
            }
        }
    }
#pragma unroll
    for (int cf = 0; cf < 4; cf++) {
        int col = wv * 64 + cf * 16 + l15;
        float bs = bias[col], gg = bng[col], bb = bnb[col];
        float h0 = gg * tanhf(acc[cf][0] + bs) + bb;
        float h1 = gg * tanhf(acc[cf][1] + bs) + bb;
        float h2 = gg * tanhf(acc[cf][2] + bs) + bb;
        float h3 = gg * tanhf(acc[cf][3] + bs) + bb;
        float p0 = 0.5f * (h0 + h1), p1 = 0.5f * (h2 + h3);
        size_t pr = (size_t)(row0 >> 1) + quad * 2;
        H1p[pr * 256 + col] = p0;
        H1p[(pr + 1) * 256 + col] = p1;
    }
}

// ---------------------------------------------------------------------------
// Pool coords: C1[b,i,:] = 0.5*(C[b,2i,:] + C[b,2i+1,:])
// ---------------------------------------------------------------------------
__global__ void c1pool_kernel(const float* __restrict__ C, float* __restrict__ C1) {
    int o = blockIdx.x * 256 + threadIdx.x;
    if (o >= 16 * 256 * 3) return;
    int d = o % 3;
    int node = o / 3;
    int b = node >> 8, i = node & 255;
    size_t src = ((size_t)(b * 512 + 2 * i)) * 3 + d;
    C1[o] = 0.5f * (C[src] + C[src + 3]);
}

// ---------------------------------------------------------------------------
// FC split-K fp32 (memory-bound on fc_w, 67 MB)
// ---------------------------------------------------------------------------
__global__ __launch_bounds__(256)
void fc_partial_kernel(const float* __restrict__ Flat, const float* __restrict__ W,
                       float* __restrict__ P) {
    int os = blockIdx.x & 7, ks = blockIdx.x >> 3;
    int o0 = os * 64;
    int m0 = ks * 1024;
    int r = threadIdx.x >> 4, c4 = threadIdx.x & 15;
    const float* fr = Flat + (size_t)r * 32768;
    float4 acc = make_float4(0.f, 0.f, 0.f, 0.f);
#pragma unroll 8
    for (int m = m0; m < m0 + 1024; m++) {
        float4 w4 = *(const float4*)&W[(size_t)m * 512 + o0 + c4 * 4];
        float x = fr[m];
        acc.x += x * w4.x; acc.y += x * w4.y;
        acc.z += x * w4.z; acc.w += x * w4.w;
    }
    *(float4*)&P[((size_t)ks * 16 + r) * 512 + o0 + c4 * 4] = acc;
}

__global__ void fc_reduce_kernel(const float* __restrict__ P, const float* __restrict__ fcb,
                                 float* __restrict__ out) {
    int idx = blockIdx.x * 256 + threadIdx.x;   // 8192 outputs
    float s = fcb[idx & 511];
    for (int ks = 0; ks < 32; ks++) s += P[(size_t)ks * 8192 + idx];
    out[idx] = 1.f / (1.f + expf(-s));
}

// ---------------------------------------------------------------------------
extern "C" void kernel_launch(void* const* d_in, const int* in_sizes, int n_in,
                              void* d_out, int out_size, void* d_ws, size_t ws_size,
                              hipStream_t stream) {
    const float* V     = (const float*)d_in[0];
    const float* C     = (const float*)d_in[1];
    const float* gk_w0 = (const float*)d_in[2];
    const float* gk_b0 = (const float*)d_in[3];
    const float* ac_w0 = (const float*)d_in[4];
    const float* ac_b0 = (const float*)d_in[5];
    const float* gc_w0 = (const float*)d_in[6];
    const float* gc_b0 = (const float*)d_in[7];
    const float* bn_g0 = (const float*)d_in[8];
    const float* bn_b0 = (const float*)d_in[9];
    const float* gk_w1 = (const float*)d_in[10];
    const float* gk_b1 = (const float*)d_in[11];
    const float* ac_w1 = (const float*)d_in[12];
    const float* ac_b1 = (const float*)d_in[13];
    const float* gc_w1 = (const float*)d_in[14];
    const float* gc_b1 = (const float*)d_in[15];
    const float* bn_g1 = (const float*)d_in[16];
    const float* bn_b1 = (const float*)d_in[17];
    const float* fc_w  = (const float*)d_in[18];
    const float* fc_b  = (const float*)d_in[19];
    float* out = (float*)d_out;

    // workspace layout: fp32 region then bf16 region (~26.7 MB total)
    float* u0  = (float*)d_ws;        // 65536
    float* w0  = u0 + 65536;          // 65536
    float* u1  = w0 + 65536;          // 32768
    float* w1  = u1 + 32768;          // 32768
    float* C1  = w1 + 32768;          // 12288
    float* H0p = C1 + 12288;          // 524288
    float* H1p = H0p + 524288;        // 524288
    float* P   = H1p + 524288;        // 262144
    ushort16* X0  = (ushort16*)(P + 262144);  // 4718592  [8192][576]
    ushort16* X1  = X0 + 4718592;             // 4718592  [4096][1152]
    ushort16* VT0 = X1 + 4718592;             // 524288   [16][64][512]; aliased as VT1
    ushort16* Wt0 = VT0 + 524288;             // 73728    [128][576]
    ushort16* Wt1 = Wt0 + 73728;              // 294912   [256][1152]
    ushort16* VT1 = VT0;  // msg0 finishes with VT0 before t_h0p writes (stream order)

    prep_kernel<<<346, 256, 0, stream>>>(V, gc_w0, gc_w1, VT0, Wt0, Wt1, X0);
    uw_kernel<<<256, 256, 0, stream>>>(V, gk_w0, gk_b0, ac_w0, ac_b0, u0, w0, 8192, 64);
    msg0_mfma<<<512, 256, 0, stream>>>(VT0, C, u0, w0, X0);
    post0_mfma<<<256, 256, 0, stream>>>(X0, Wt0, gc_b0, bn_g0, bn_b0, H0p, X1);
    c1pool_kernel<<<48, 256, 0, stream>>>(C, C1);
    t_h0p_kernel<<<128, 256, 0, stream>>>(H0p, VT1);
    uw_kernel<<<128, 256, 0, stream>>>(H0p, gk_w1, gk_b1, ac_w1, ac_b1, u1, w1, 4096, 128);
    msg1_mfma<<<256, 256, 0, stream>>>(VT1, C1, u1, w1, X1);
    post1_mfma<<<256, 256, 0, stream>>>(X1, Wt1, gc_b1, bn_g1, bn_b1, H1p);
    fc_partial_kernel<<<256, 256, 0, stream>>>(H1p, fc_w, P);
    fc_reduce_kernel<<<32, 256, 0, stream>>>(P, fc_b, out);
}

// Round 3
// 264.027 us; speedup vs baseline: 2.2606x; 1.7271x over previous
//
#include <hip/hip_runtime.h>
#include <math.h>

#define KK 8
#define EPSF 1e-9f

typedef unsigned int   uint32;
typedef unsigned short u16;
typedef __attribute__((ext_vector_type(8))) short bf16x8;
typedef __attribute__((ext_vector_type(4))) float f32x4;

#define MFMA_16x16x32(a, b, c) __builtin_amdgcn_mfma_f32_16x16x32_bf16(a, b, c, 0, 0, 0)

typedef __attribute__((address_space(1))) const unsigned int glob_cu32;
typedef __attribute__((address_space(3))) unsigned int lds_u32;
// async global->LDS DMA, 16B per lane; LDS dest = wave-uniform base + lane*16
__device__ __forceinline__ void g2l16(const void* gsrc, void* ldst) {
    __builtin_amdgcn_global_load_lds((glob_cu32*)gsrc, (lds_u32*)ldst, 16, 0, 0);
}

// swizzled ushort index of logical octet o (8 bf16) in a [row][64] LDS tile
__device__ __forceinline__ int swz(int row, int o) {
    return (row << 6) + (((o) ^ (row & 7)) << 3);
}

__device__ __forceinline__ float softplusf(float x) {
    return x > 0.0f ? x + log1pf(expf(-x)) : log1pf(expf(x));
}
__device__ __forceinline__ float sigmoidf_(float x) {
    return 1.0f / (1.0f + expf(-x));
}
// fp32 -> bf16 round-to-nearest-even
__device__ __forceinline__ u16 f2bf(float f) {
    union { float f; uint32 u; } v; v.f = f;
    uint32 u = v.u;
    return (u16)((u + 0x7FFFu + ((u >> 16) & 1u)) >> 16);
}

// ---------------------------------------------------------------------------
// prep: V->VT0 bf16 [16][64][512] (transposed), gc_w0->Wt0 bf16 [128][576],
//       gc_w1->Wt1 bf16 [256][1152], V->X0[:, :64] bf16 (straight).
// ---------------------------------------------------------------------------
__global__ __launch_bounds__(256)
void prep_kernel(const float* __restrict__ V, const float* __restrict__ W0,
                 const float* __restrict__ W1, u16* __restrict__ VT0,
                 u16* __restrict__ Wt0, u16* __restrict__ Wt1,
                 u16* __restrict__ X0) {
    __shared__ float s[64][65];
    int blk = blockIdx.x, tid = threadIdx.x;
    if (blk < 128) {            // V [16][512][64] -> VT0 [16][64][512]
        int b = blk >> 3, rt = blk & 7;
#pragma unroll
        for (int t = 0; t < 16; t++) {
            int idx = t * 256 + tid; int r = idx >> 6, c = idx & 63;
            s[r][c] = V[((size_t)b * 512 + rt * 64 + r) * 64 + c];
        }
        __syncthreads();
#pragma unroll
        for (int t = 0; t < 16; t++) {
            int idx = t * 256 + tid; int f = idx >> 6, j = idx & 63;
            VT0[((size_t)b * 64 + f) * 512 + rt * 64 + j] = f2bf(s[j][f]);
        }
    } else if (blk < 146) {     // W0 [576][128] -> Wt0 [128][576]
        int t0 = blk - 128; int rt = t0 >> 1, ct = t0 & 1;
#pragma unroll
        for (int t = 0; t < 16; t++) {
            int idx = t * 256 + tid; int r = idx >> 6, c = idx & 63;
            s[r][c] = W0[((size_t)rt * 64 + r) * 128 + ct * 64 + c];
        }
        __syncthreads();
#pragma unroll
        for (int t = 0; t < 16; t++) {
            int idx = t * 256 + tid; int f = idx >> 6, j = idx & 63;
            Wt0[((size_t)ct * 64 + f) * 576 + rt * 64 + j] = f2bf(s[j][f]);
        }
    } else if (blk < 218) {     // W1 [1152][256] -> Wt1 [256][1152]
        int t0 = blk - 146; int rt = t0 >> 2, ct = t0 & 3;
#pragma unroll
        for (int t = 0; t < 16; t++) {
            int idx = t * 256 + tid; int r = idx >> 6, c = idx & 63;
            s[r][c] = W1[((size_t)rt * 64 + r) * 256 + ct * 64 + c];
        }
        __syncthreads();
#pragma unroll
        for (int t = 0; t < 16; t++) {
            int idx = t * 256 + tid; int f = idx >> 6, j = idx & 63;
            Wt1[((size_t)ct * 64 + f) * 1152 + rt * 64 + j] = f2bf(s[j][f]);
        }
    } else {                    // V flat -> X0[:, 0:64] bf16
        int t0 = blk - 218;
#pragma unroll
        for (int q = 0; q < 16; q++) {
            int e = t0 * 4096 + q * 256 + tid;
            int row = e >> 6, c = e & 63;
            X0[(size_t)row * 576 + c] = f2bf(V[e]);
        }
    }
}

// ---------------------------------------------------------------------------
// transpose H0p [16][256][128] fp32 -> VT1 [16][128][256] bf16
// ---------------------------------------------------------------------------
__global__ __launch_bounds__(256)
void t_h0p_kernel(const float* __restrict__ H0p, u16* __restrict__ VT1) {
    __shared__ float s[64][65];
    int blk = blockIdx.x, tid = threadIdx.x;
    int b = blk >> 3, rt = (blk >> 1) & 3, ct = blk & 1;
#pragma unroll
    for (int t = 0; t < 16; t++) {
        int idx = t * 256 + tid; int r = idx >> 6, c = idx & 63;
        s[r][c] = H0p[((size_t)b * 256 + rt * 64 + r) * 128 + ct * 64 + c];
    }
    __syncthreads();
#pragma unroll
    for (int t = 0; t < 16; t++) {
        int idx = t * 256 + tid; int f = idx >> 6, j = idx & 63;
        VT1[((size_t)b * 128 + ct * 64 + f) * 256 + rt * 64 + j] = f2bf(s[j][f]);
    }
}

// ---------------------------------------------------------------------------
// u = softplus(X @ gw + gb), w = sigmoid(X @ aw + ab); compile-time F
// ---------------------------------------------------------------------------
template<int F>
__global__ __launch_bounds__(256)
void uw_kernel(const float* __restrict__ X, const float* __restrict__ gw,
               const float* __restrict__ gb, const float* __restrict__ aw,
               const float* __restrict__ ab, float* __restrict__ u,
               float* __restrict__ w, int rows) {
    int t = blockIdx.x * 256 + threadIdx.x;
    if (t >= rows * KK) return;
    int row = t >> 3, k = t & 7;
    const float4* xr = (const float4*)(X + (size_t)row * F);
    float su = 0.f, sw = 0.f;
#pragma unroll
    for (int f4 = 0; f4 < F / 4; f4++) {
        float4 x = xr[f4];
        su += x.x * gw[(f4 * 4 + 0) * 8 + k] + x.y * gw[(f4 * 4 + 1) * 8 + k]
            + x.z * gw[(f4 * 4 + 2) * 8 + k] + x.w * gw[(f4 * 4 + 3) * 8 + k];
        sw += x.x * aw[(f4 * 4 + 0) * 8 + k] + x.y * aw[(f4 * 4 + 1) * 8 + k]
            + x.z * aw[(f4 * 4 + 2) * 8 + k] + x.w * aw[(f4 * 4 + 3) * 8 + k];
    }
    u[t] = softplusf(su + gb[k]);
    w[t] = sigmoidf_(sw + ab[k]);
}

// ---------------------------------------------------------------------------
// msg0 MFMA: M0-tile = A(128 ik x 512 j) * V(512 j x 64 f), bf16 mfma.
// DMA-staged V^T, swizzled LDS, fused d2/cos/A-gen. Grid 512 = 16b x 32 tiles.
// ---------------------------------------------------------------------------
__global__ __launch_bounds__(256)
void msg0_mfma(const u16* __restrict__ VT0, const float* __restrict__ C,
               const float* __restrict__ u0, const float* __restrict__ w0,
               u16* __restrict__ X0) {
    int b = blockIdx.x >> 5, i0 = (blockIdx.x & 31) * 16;
    int tid = threadIdx.x;
    int wv = tid >> 6, lane = tid & 63, quad = lane >> 4, l15 = lane & 15;

    __shared__ __align__(16) u16 s_vT[64 * 64];      // 8 KB  [f][j] swizzled
    __shared__ __align__(16) u16 s_A[128 * 64];      // 16 KB [ik][j] swizzled
    __shared__ __align__(16) float s_cj[64][4];      // x,y,z,l2
    __shared__ __align__(16) float s_ci[16][4];
    __shared__ __align__(16) float s_u[16][KK];
    __shared__ __align__(16) float s_w[16][KK];

    if (tid < 16) {
        const float* cp = C + ((size_t)b * 512 + i0 + tid) * 3;
        float x = cp[0], y = cp[1], z = cp[2];
        s_ci[tid][0] = x; s_ci[tid][1] = y; s_ci[tid][2] = z;
        s_ci[tid][3] = x * x + y * y + z * z;
    }
    if (tid < 128) {
        int i = tid >> 3, k = tid & 7;
        size_t idx = ((size_t)b * 512 + i0 + i) * KK + k;
        s_u[i][k] = u0[idx];
        s_w[i][k] = w0[idx];
    }

    f32x4 acc[2][4] = {};

    for (int j0 = 0; j0 < 512; j0 += 64) {
        __syncthreads();
        // stage V^T tile [64 f][64 j] via DMA (2 passes of 4KB)
#pragma unroll
        for (int p = 0; p < 2; p++) {
            int s = p * 256 + wv * 64 + lane;
            int f = s >> 3, op = s & 7;
            g2l16(VT0 + ((size_t)b * 64 + f) * 512 + j0 + ((op ^ (f & 7)) << 3),
                  (void*)(s_vT + (p * 256 + wv * 64) * 8));
        }
        if (tid < 64) {
            const float* cp = C + ((size_t)b * 512 + j0 + tid) * 3;
            float x = cp[0], y = cp[1], z = cp[2];
            s_cj[tid][0] = x; s_cj[tid][1] = y; s_cj[tid][2] = z;
            s_cj[tid][3] = x * x + y * y + z * z;
        }
        __syncthreads();
        // fused d2/cos/A-gen: thread -> (i = t*4+wv, j = lane), all 8 k
#pragma unroll
        for (int t = 0; t < 4; t++) {
            int i = t * 4 + wv, j = lane;
            float cix = s_ci[i][0], ciy = s_ci[i][1], ciz = s_ci[i][2], l2i = s_ci[i][3];
            float cjx = s_cj[j][0], cjy = s_cj[j][1], cjz = s_cj[j][2], l2j = s_cj[j][3];
            float dot = cix * cjx + ciy * cjy + ciz * cjz;
            float d2 = fabsf(l2i + l2j - 2.f * dot) + EPSF;
            float cs = dot / sqrtf((l2i + EPSF) * (l2j + EPSF));
            f32x4 u01 = *(const f32x4*)&s_u[i][0];
            f32x4 u23 = *(const f32x4*)&s_u[i][4];
            f32x4 w01 = *(const f32x4*)&s_w[i][0];
            f32x4 w23 = *(const f32x4*)&s_w[i][4];
#pragma unroll
            for (int k = 0; k < 4; k++) {
                float a = __expf(-d2 * u01[k]) * (w01[k] * cs + 1.f - w01[k]);
                int row = i * 8 + k;
                s_A[(row << 6) + (((j >> 3) ^ (row & 7)) << 3) + (j & 7)] = f2bf(a);
            }
#pragma unroll
            for (int k = 0; k < 4; k++) {
                float a = __expf(-d2 * u23[k]) * (w23[k] * cs + 1.f - w23[k]);
                int row = i * 8 + 4 + k;
                s_A[(row << 6) + (((j >> 3) ^ (row & 7)) << 3) + (j & 7)] = f2bf(a);
            }
        }
        __syncthreads();
#pragma unroll
        for (int ks = 0; ks < 2; ks++) {
            int o = ks * 4 + quad;
            bf16x8 a0 = *(const bf16x8*)&s_A[swz(wv * 32 + l15, o)];
            bf16x8 a1 = *(const bf16x8*)&s_A[swz(wv * 32 + 16 + l15, o)];
#pragma unroll
            for (int cf = 0; cf < 4; cf++) {
                bf16x8 bv = *(const bf16x8*)&s_vT[swz(cf * 16 + l15, o)];
                acc[0][cf] = MFMA_16x16x32(a0, bv, acc[0][cf]);
                acc[1][cf] = MFMA_16x16x32(a1, bv, acc[1][cf]);
            }
        }
    }
#pragma unroll
    for (int rf = 0; rf < 2; rf++)
#pragma unroll
        for (int cf = 0; cf < 4; cf++)
#pragma unroll
            for (int r = 0; r < 4; r++) {
                int arow = wv * 32 + rf * 16 + quad * 4 + r;
                int i = arow >> 3, k = arow & 7;
                X0[((size_t)b * 512 + i0 + i) * 576 + 64 + k * 64 + cf * 16 + l15] =
                    f2bf(acc[rf][cf][r]);
            }
}

// ---------------------------------------------------------------------------
// msg1 MFMA: A(128 ik x 256 j) * H(256 j x 128 f). Writes X1[:, 128:1152].
// Grid 256 = 16 b x 16 i-tiles.
// ---------------------------------------------------------------------------
__global__ __launch_bounds__(256)
void msg1_mfma(const u16* __restrict__ VT1, const float* __restrict__ C1,
               const float* __restrict__ u1, const float* __restrict__ w1,
               u16* __restrict__ X1) {
    int b = blockIdx.x >> 4, i0 = (blockIdx.x & 15) * 16;
    int tid = threadIdx.x;
    int wv = tid >> 6, lane = tid & 63, quad = lane >> 4, l15 = lane & 15;

    __shared__ __align__(16) u16 s_vT[128 * 64];     // 16 KB [f][j] swizzled
    __shared__ __align__(16) u16 s_A[128 * 64];      // 16 KB [ik][j] swizzled
    __shared__ __align__(16) float s_cj[64][4];
    __shared__ __align__(16) float s_ci[16][4];
    __shared__ __align__(16) float s_u[16][KK];
    __shared__ __align__(16) float s_w[16][KK];

    if (tid < 16) {
        const float* cp = C1 + ((size_t)b * 256 + i0 + tid) * 3;
        float x = cp[0], y = cp[1], z = cp[2];
        s_ci[tid][0] = x; s_ci[tid][1] = y; s_ci[tid][2] = z;
        s_ci[tid][3] = x * x + y * y + z * z;
    }
    if (tid < 128) {
        int i = tid >> 3, k = tid & 7;
        size_t idx = ((size_t)b * 256 + i0 + i) * KK + k;
        s_u[i][k] = u1[idx];
        s_w[i][k] = w1[idx];
    }

    f32x4 acc[2][8] = {};

    for (int j0 = 0; j0 < 256; j0 += 64) {
        __syncthreads();
        // stage H^T tile [128 f][64 j] via DMA (4 passes)
#pragma unroll
        for (int p = 0; p < 4; p++) {
            int s = p * 256 + wv * 64 + lane;
            int f = s >> 3, op = s & 7;
            g2l16(VT1 + ((size_t)b * 128 + f) * 256 + j0 + ((op ^ (f & 7)) << 3),
                  (void*)(s_vT + (p * 256 + wv * 64) * 8));
        }
        if (tid < 64) {
            const float* cp = C1 + ((size_t)b * 256 + j0 + tid) * 3;
            float x = cp[0], y = cp[1], z = cp[2];
            s_cj[tid][0] = x; s_cj[tid][1] = y; s_cj[tid][2] = z;
            s_cj[tid][3] = x * x + y * y + z * z;
        }
        __syncthreads();
#pragma unroll
        for (int t = 0; t < 4; t++) {
            int i = t * 4 + wv, j = lane;
            float cix = s_ci[i][0], ciy = s_ci[i][1], ciz = s_ci[i][2], l2i = s_ci[i][3];
            float cjx = s_cj[j][0], cjy = s_cj[j][1], cjz = s_cj[j][2], l2j = s_cj[j][3];
            float dot = cix * cjx + ciy * cjy + ciz * cjz;
            float d2 = fabsf(l2i + l2j - 2.f * dot) + EPSF;
            float cs = dot / sqrtf((l2i + EPSF) * (l2j + EPSF));
            f32x4 u01 = *(const f32x4*)&s_u[i][0];
            f32x4 u23 = *(const f32x4*)&s_u[i][4];
            f32x4 w01 = *(const f32x4*)&s_w[i][0];
            f32x4 w23 = *(const f32x4*)&s_w[i][4];
#pragma unroll
            for (int k = 0; k < 4; k++) {
                float a = __expf(-d2 * u01[k]) * (w01[k] * cs + 1.f - w01[k]);
                int row = i * 8 + k;
                s_A[(row << 6) + (((j >> 3) ^ (row & 7)) << 3) + (j & 7)] = f2bf(a);
            }
#pragma unroll
            for (int k = 0; k < 4; k++) {
                float a = __expf(-d2 * u23[k]) * (w23[k] * cs + 1.f - w23[k]);
                int row = i * 8 + 4 + k;
                s_A[(row << 6) + (((j >> 3) ^ (row & 7)) << 3) + (j & 7)] = f2bf(a);
            }
        }
        __syncthreads();
#pragma unroll
        for (int ks = 0; ks < 2; ks++) {
            int o = ks * 4 + quad;
            bf16x8 a0 = *(const bf16x8*)&s_A[swz(wv * 32 + l15, o)];
            bf16x8 a1 = *(const bf16x8*)&s_A[swz(wv * 32 + 16 + l15, o)];
#pragma unroll
            for (int cf = 0; cf < 8; cf++) {
                bf16x8 bv = *(const bf16x8*)&s_vT[swz(cf * 16 + l15, o)];
                acc[0][cf] = MFMA_16x16x32(a0, bv, acc[0][cf]);
                acc[1][cf] = MFMA_16x16x32(a1, bv, acc[1][cf]);
            }
        }
    }
#pragma unroll
    for (int rf = 0; rf < 2; rf++)
#pragma unroll
        for (int cf = 0; cf < 8; cf++)
#pragma unroll
            for (int r = 0; r < 4; r++) {
                int arow = wv * 32 + rf * 16 + quad * 4 + r;
                int i = arow >> 3, k = arow & 7;
                X1[((size_t)b * 256 + i0 + i) * 1152 + 128 + k * 128 + cf * 16 + l15] =
                    f2bf(acc[rf][cf][r]);
            }
}

// ---------------------------------------------------------------------------
// post0 MFMA GEMM: [8192 x 576] @ [576 x 128] -> tanh/bn -> pool.
// Tile 32x64, grid 512 = 256 rowtiles x 2 coltiles. DMA staging, swizzled.
// ---------------------------------------------------------------------------
__global__ __launch_bounds__(256)
void post0_mfma(const u16* __restrict__ X0, const u16* __restrict__ Wt,
                const float* __restrict__ bias, const float* __restrict__ bng,
                const float* __restrict__ bnb, float* __restrict__ H0p,
                u16* __restrict__ X1) {
    int row0 = (blockIdx.x >> 1) * 32, col0 = (blockIdx.x & 1) * 64;
    int tid = threadIdx.x;
    int wv = tid >> 6, lane = tid & 63, quad = lane >> 4, l15 = lane & 15;
    int rw = wv & 1, cw = wv >> 1;

    __shared__ __align__(16) u16 s_X[32 * 64];   // 4 KB
    __shared__ __align__(16) u16 s_W[64 * 64];   // 8 KB

    f32x4 acc[2] = {};

    for (int kc = 0; kc < 576; kc += 64) {
        __syncthreads();
        {   // X tile: 32 rows, 1 pass
            int s = wv * 64 + lane;
            int r = s >> 3, op = s & 7;
            g2l16(X0 + ((size_t)row0 + r) * 576 + kc + ((op ^ (r & 7)) << 3),
                  (void*)(s_X + (wv * 64) * 8));
        }
#pragma unroll
        for (int p = 0; p < 2; p++) {   // W tile: 64 rows, 2 passes
            int s = p * 256 + wv * 64 + lane;
            int c = s >> 3, op = s & 7;
            g2l16(Wt + ((size_t)col0 + c) * 576 + kc + ((op ^ (c & 7)) << 3),
                  (void*)(s_W + (p * 256 + wv * 64) * 8));
        }
        __syncthreads();
#pragma unroll
        for (int ks = 0; ks < 2; ks++) {
            int o = ks * 4 + quad;
            bf16x8 av = *(const bf16x8*)&s_X[swz(rw * 16 + l15, o)];
#pragma unroll
            for (int cf = 0; cf < 2; cf++) {
                bf16x8 bv = *(const bf16x8*)&s_W[swz(cw * 32 + cf * 16 + l15, o)];
                acc[cf] = MFMA_16x16x32(av, bv, acc[cf]);
            }
        }
    }
#pragma unroll
    for (int cf = 0; cf < 2; cf++) {
        int col = col0 + cw * 32 + cf * 16 + l15;
        float bs = bias[col], gg = bng[col], bb = bnb[col];
        float h0 = gg * tanhf(acc[cf][0] + bs) + bb;
        float h1 = gg * tanhf(acc[cf][1] + bs) + bb;
        float h2 = gg * tanhf(acc[cf][2] + bs) + bb;
        float h3 = gg * tanhf(acc[cf][3] + bs) + bb;
        float p0 = 0.5f * (h0 + h1), p1 = 0.5f * (h2 + h3);
        size_t pr = (size_t)(row0 >> 1) + rw * 8 + quad * 2;
        H0p[pr * 128 + col] = p0;
        H0p[(pr + 1) * 128 + col] = p1;
        X1[pr * 1152 + col] = f2bf(p0);
        X1[(pr + 1) * 1152 + col] = f2bf(p1);
    }
}

// ---------------------------------------------------------------------------
// post1 MFMA GEMM: [4096 x 1152] @ [1152 x 256] -> tanh/bn -> pool.
// Tile 32x64, grid 512 = 128 rowtiles x 4 coltiles. DMA staging, swizzled.
// ---------------------------------------------------------------------------
__global__ __launch_bounds__(256)
void post1_mfma(const u16* __restrict__ X1, const u16* __restrict__ Wt,
                const float* __restrict__ bias, const float* __restrict__ bng,
                const float* __restrict__ bnb, float* __restrict__ H1p) {
    int row0 = (blockIdx.x >> 2) * 32, col0 = (blockIdx.x & 3) * 64;
    int tid = threadIdx.x;
    int wv = tid >> 6, lane = tid & 63, quad = lane >> 4, l15 = lane & 15;
    int rw = wv & 1, cw = wv >> 1;

    __shared__ __align__(16) u16 s_X[32 * 64];
    __shared__ __align__(16) u16 s_W[64 * 64];

    f32x4 acc[2] = {};

    for (int kc = 0; kc < 1152; kc += 64) {
        __syncthreads();
        {
            int s = wv * 64 + lane;
            int r = s >> 3, op = s & 7;
            g2l16(X1 + ((size_t)row0 + r) * 1152 + kc + ((op ^ (r & 7)) << 3),
                  (void*)(s_X + (wv * 64) * 8));
        }
#pragma unroll
        for (int p = 0; p < 2; p++) {
            int s = p * 256 + wv * 64 + lane;
            int c = s >> 3, op = s & 7;
            g2l16(Wt + ((size_t)col0 + c) * 1152 + kc + ((op ^ (c & 7)) << 3),
                  (void*)(s_W + (p * 256 + wv * 64) * 8));
        }
        __syncthreads();
#pragma unroll
        for (int ks = 0; ks < 2; ks++) {
            int o = ks * 4 + quad;
            bf16x8 av = *(const bf16x8*)&s_X[swz(rw * 16 + l15, o)];
#pragma unroll
            for (int cf = 0; cf < 2; cf++) {
                bf16x8 bv = *(const bf16x8*)&s_W[swz(cw * 32 + cf * 16 + l15, o)];
                acc[cf] = MFMA_16x16x32(av, bv, acc[cf]);
            }
        }
    }
#pragma unroll
    for (int cf = 0; cf < 2; cf++) {
        int col = col0 + cw * 32 + cf * 16 + l15;
        float bs = bias[col], gg = bng[col], bb = bnb[col];
        float h0 = gg * tanhf(acc[cf][0] + bs) + bb;
        float h1 = gg * tanhf(acc[cf][1] + bs) + bb;
        float h2 = gg * tanhf(acc[cf][2] + bs) + bb;
        float h3 = gg * tanhf(acc[cf][3] + bs) + bb;
        float p0 = 0.5f * (h0 + h1), p1 = 0.5f * (h2 + h3);
        size_t pr = (size_t)(row0 >> 1) + rw * 8 + quad * 2;
        H1p[pr * 256 + col] = p0;
        H1p[(pr + 1) * 256 + col] = p1;
    }
}

// ---------------------------------------------------------------------------
// Pool coords: C1[b,i,:] = 0.5*(C[b,2i,:] + C[b,2i+1,:])
// ---------------------------------------------------------------------------
__global__ void c1pool_kernel(const float* __restrict__ C, float* __restrict__ C1) {
    int o = blockIdx.x * 256 + threadIdx.x;
    if (o >= 16 * 256 * 3) return;
    int d = o % 3;
    int node = o / 3;
    int b = node >> 8, i = node & 255;
    size_t src = ((size_t)(b * 512 + 2 * i)) * 3 + d;
    C1[o] = 0.5f * (C[src] + C[src + 3]);
}

// ---------------------------------------------------------------------------
// FC split-K fp32: two-phase unroll-16 so 16 float4 W loads stay in flight.
// ---------------------------------------------------------------------------
__global__ __launch_bounds__(256)
void fc_partial_kernel(const float* __restrict__ Flat, const float* __restrict__ W,
                       float* __restrict__ P) {
    int os = blockIdx.x & 7, ks = blockIdx.x >> 3;
    int o0 = os * 64;
    int m0 = ks * 1024;
    int r = threadIdx.x >> 4, c4 = threadIdx.x & 15;
    const float* fr = Flat + (size_t)r * 32768;
    const float4* W4 = (const float4*)W;
    float4 acc = make_float4(0.f, 0.f, 0.f, 0.f);
    for (int mm = m0; mm < m0 + 1024; mm += 16) {
        float4 wv[16];
        float xv[16];
#pragma unroll
        for (int i = 0; i < 16; i++)
            wv[i] = W4[(size_t)(mm + i) * 128 + (o0 >> 2) + c4];
#pragma unroll
        for (int i = 0; i < 16; i++)
            xv[i] = fr[mm + i];
#pragma unroll
        for (int i = 0; i < 16; i++) {
            acc.x += xv[i] * wv[i].x; acc.y += xv[i] * wv[i].y;
            acc.z += xv[i] * wv[i].z; acc.w += xv[i] * wv[i].w;
        }
    }
    *(float4*)&P[((size_t)ks * 16 + r) * 512 + o0 + c4 * 4] = acc;
}

__global__ void fc_reduce_kernel(const float* __restrict__ P, const float* __restrict__ fcb,
                                 float* __restrict__ out) {
    int idx = blockIdx.x * 256 + threadIdx.x;   // 8192 outputs
    float s = fcb[idx & 511];
    for (int ks = 0; ks < 32; ks++) s += P[(size_t)ks * 8192 + idx];
    out[idx] = 1.f / (1.f + expf(-s));
}

// ---------------------------------------------------------------------------
extern "C" void kernel_launch(void* const* d_in, const int* in_sizes, int n_in,
                              void* d_out, int out_size, void* d_ws, size_t ws_size,
                              hipStream_t stream) {
    const float* V     = (const float*)d_in[0];
    const float* C     = (const float*)d_in[1];
    const float* gk_w0 = (const float*)d_in[2];
    const float* gk_b0 = (const float*)d_in[3];
    const float* ac_w0 = (const float*)d_in[4];
    const float* ac_b0 = (const float*)d_in[5];
    const float* gc_w0 = (const float*)d_in[6];
    const float* gc_b0 = (const float*)d_in[7];
    const float* bn_g0 = (const float*)d_in[8];
    const float* bn_b0 = (const float*)d_in[9];
    const float* gk_w1 = (const float*)d_in[10];
    const float* gk_b1 = (const float*)d_in[11];
    const float* ac_w1 = (const float*)d_in[12];
    const float* ac_b1 = (const float*)d_in[13];
    const float* gc_w1 = (const float*)d_in[14];
    const float* gc_b1 = (const float*)d_in[15];
    const float* bn_g1 = (const float*)d_in[16];
    const float* bn_b1 = (const float*)d_in[17];
    const float* fc_w  = (const float*)d_in[18];
    const float* fc_b  = (const float*)d_in[19];
    float* out = (float*)d_out;

    float* u0  = (float*)d_ws;        // 65536
    float* w0  = u0 + 65536;          // 65536
    float* u1  = w0 + 65536;          // 32768
    float* w1  = u1 + 32768;          // 32768
    float* C1  = w1 + 32768;          // 12288
    float* H0p = C1 + 12288;          // 524288
    float* H1p = H0p + 524288;        // 524288
    float* P   = H1p + 524288;        // 262144
    u16* X0  = (u16*)(P + 262144);    // 4718592  [8192][576]
    u16* X1  = X0 + 4718592;          // 4718592  [4096][1152]
    u16* VT0 = X1 + 4718592;          // 524288   [16][64][512]; aliased as VT1
    u16* Wt0 = VT0 + 524288;          // 73728    [128][576]
    u16* Wt1 = Wt0 + 73728;           // 294912   [256][1152]
    u16* VT1 = VT0;  // msg0 finishes with VT0 before t_h0p writes (stream order)

    prep_kernel<<<346, 256, 0, stream>>>(V, gc_w0, gc_w1, VT0, Wt0, Wt1, X0);
    uw_kernel<64><<<256, 256, 0, stream>>>(V, gk_w0, gk_b0, ac_w0, ac_b0, u0, w0, 8192);
    msg0_mfma<<<512, 256, 0, stream>>>(VT0, C, u0, w0, X0);
    post0_mfma<<<512, 256, 0, stream>>>(X0, Wt0, gc_b0, bn_g0, bn_b0, H0p, X1);
    c1pool_kernel<<<48, 256, 0, stream>>>(C, C1);
    t_h0p_kernel<<<128, 256, 0, stream>>>(H0p, VT1);
    uw_kernel<128><<<128, 256, 0, stream>>>(H0p, gk_w1, gk_b1, ac_w1, ac_b1, u1, w1, 4096);
    msg1_mfma<<<256, 256, 0, stream>>>(VT1, C1, u1, w1, X1);
    post1_mfma<<<512, 256, 0, stream>>>(X1, Wt1, gc_b1, bn_g1, bn_b1, H1p);
    fc_partial_kernel<<<256, 256, 0, stream>>>(H1p, fc_w, P);
    fc_reduce_kernel<<<32, 256, 0, stream>>>(P, fc_b, out);
}

// Round 4
// 228.122 us; speedup vs baseline: 2.6164x; 1.1574x over previous
//
#include <hip/hip_runtime.h>
#include <math.h>

#define KK 8
#define EPSF 1e-9f

typedef unsigned int   uint32;
typedef unsigned short u16;
typedef __attribute__((ext_vector_type(8))) short bf16x8;
typedef __attribute__((ext_vector_type(4))) float f32x4;

#define MFMA_16x16x32(a, b, c) __builtin_amdgcn_mfma_f32_16x16x32_bf16(a, b, c, 0, 0, 0)

typedef __attribute__((address_space(1))) const unsigned int glob_cu32;
typedef __attribute__((address_space(3))) unsigned int lds_u32;
// async global->LDS DMA, 16B per lane; LDS dest = wave-uniform base + lane*16
__device__ __forceinline__ void g2l16(const void* gsrc, void* ldst) {
    __builtin_amdgcn_global_load_lds((glob_cu32*)gsrc, (lds_u32*)ldst, 16, 0, 0);
}

// swizzled ushort index of logical octet o (8 bf16) in a [row][64] LDS tile
__device__ __forceinline__ int swz(int row, int o) {
    return (row << 6) + (((o) ^ (row & 7)) << 3);
}

__device__ __forceinline__ float softplusf(float x) {
    return x > 0.0f ? x + log1pf(expf(-x)) : log1pf(expf(x));
}
__device__ __forceinline__ float sigmoidf_(float x) {
    return 1.0f / (1.0f + expf(-x));
}
// fp32 -> bf16 round-to-nearest-even
__device__ __forceinline__ u16 f2bf(float f) {
    union { float f; uint32 u; } v; v.f = f;
    uint32 u = v.u;
    return (u16)((u + 0x7FFFu + ((u >> 16) & 1u)) >> 16);
}

// ---------------------------------------------------------------------------
// prep: V->VT0 bf16 [16][64][512] (transposed), gc_w0->Wt0 bf16 [128][576],
//       gc_w1->Wt1 bf16 [256][1152], V->X0[:, :64] bf16 (straight).
// ---------------------------------------------------------------------------
__global__ __launch_bounds__(256)
void prep_kernel(const float* __restrict__ V, const float* __restrict__ W0,
                 const float* __restrict__ W1, u16* __restrict__ VT0,
                 u16* __restrict__ Wt0, u16* __restrict__ Wt1,
                 u16* __restrict__ X0) {
    __shared__ float s[64][65];
    int blk = blockIdx.x, tid = threadIdx.x;
    if (blk < 128) {            // V [16][512][64] -> VT0 [16][64][512]
        int b = blk >> 3, rt = blk & 7;
#pragma unroll
        for (int t = 0; t < 16; t++) {
            int idx = t * 256 + tid; int r = idx >> 6, c = idx & 63;
            s[r][c] = V[((size_t)b * 512 + rt * 64 + r) * 64 + c];
        }
        __syncthreads();
#pragma unroll
        for (int t = 0; t < 16; t++) {
            int idx = t * 256 + tid; int f = idx >> 6, j = idx & 63;
            VT0[((size_t)b * 64 + f) * 512 + rt * 64 + j] = f2bf(s[j][f]);
        }
    } else if (blk < 146) {     // W0 [576][128] -> Wt0 [128][576]
        int t0 = blk - 128; int rt = t0 >> 1, ct = t0 & 1;
#pragma unroll
        for (int t = 0; t < 16; t++) {
            int idx = t * 256 + tid; int r = idx >> 6, c = idx & 63;
            s[r][c] = W0[((size_t)rt * 64 + r) * 128 + ct * 64 + c];
        }
        __syncthreads();
#pragma unroll
        for (int t = 0; t < 16; t++) {
            int idx = t * 256 + tid; int f = idx >> 6, j = idx & 63;
            Wt0[((size_t)ct * 64 + f) * 576 + rt * 64 + j] = f2bf(s[j][f]);
        }
    } else if (blk < 218) {     // W1 [1152][256] -> Wt1 [256][1152]
        int t0 = blk - 146; int rt = t0 >> 2, ct = t0 & 3;
#pragma unroll
        for (int t = 0; t < 16; t++) {
            int idx = t * 256 + tid; int r = idx >> 6, c = idx & 63;
            s[r][c] = W1[((size_t)rt * 64 + r) * 256 + ct * 64 + c];
        }
        __syncthreads();
#pragma unroll
        for (int t = 0; t < 16; t++) {
            int idx = t * 256 + tid; int f = idx >> 6, j = idx & 63;
            Wt1[((size_t)ct * 64 + f) * 1152 + rt * 64 + j] = f2bf(s[j][f]);
        }
    } else {                    // V flat -> X0[:, 0:64] bf16
        int t0 = blk - 218;
#pragma unroll
        for (int q = 0; q < 16; q++) {
            int e = t0 * 4096 + q * 256 + tid;
            int row = e >> 6, c = e & 63;
            X0[(size_t)row * 576 + c] = f2bf(V[e]);
        }
    }
}

// ---------------------------------------------------------------------------
// transpose H0p [16][256][128] fp32 -> VT1 [16][128][256] bf16
// ---------------------------------------------------------------------------
__global__ __launch_bounds__(256)
void t_h0p_kernel(const float* __restrict__ H0p, u16* __restrict__ VT1) {
    __shared__ float s[64][65];
    int blk = blockIdx.x, tid = threadIdx.x;
    int b = blk >> 3, rt = (blk >> 1) & 3, ct = blk & 1;
#pragma unroll
    for (int t = 0; t < 16; t++) {
        int idx = t * 256 + tid; int r = idx >> 6, c = idx & 63;
        s[r][c] = H0p[((size_t)b * 256 + rt * 64 + r) * 128 + ct * 64 + c];
    }
    __syncthreads();
#pragma unroll
    for (int t = 0; t < 16; t++) {
        int idx = t * 256 + tid; int f = idx >> 6, j = idx & 63;
        VT1[((size_t)b * 128 + ct * 64 + f) * 256 + rt * 64 + j] = f2bf(s[j][f]);
    }
}

// ---------------------------------------------------------------------------
// u = softplus(X @ gw + gb), w = sigmoid(X @ aw + ab); compile-time F
// ---------------------------------------------------------------------------
template<int F>
__global__ __launch_bounds__(256)
void uw_kernel(const float* __restrict__ X, const float* __restrict__ gw,
               const float* __restrict__ gb, const float* __restrict__ aw,
               const float* __restrict__ ab, float* __restrict__ u,
               float* __restrict__ w, int rows) {
    int t = blockIdx.x * 256 + threadIdx.x;
    if (t >= rows * KK) return;
    int row = t >> 3, k = t & 7;
    const float4* xr = (const float4*)(X + (size_t)row * F);
    float su = 0.f, sw = 0.f;
#pragma unroll
    for (int f4 = 0; f4 < F / 4; f4++) {
        float4 x = xr[f4];
        su += x.x * gw[(f4 * 4 + 0) * 8 + k] + x.y * gw[(f4 * 4 + 1) * 8 + k]
            + x.z * gw[(f4 * 4 + 2) * 8 + k] + x.w * gw[(f4 * 4 + 3) * 8 + k];
        sw += x.x * aw[(f4 * 4 + 0) * 8 + k] + x.y * aw[(f4 * 4 + 1) * 8 + k]
            + x.z * aw[(f4 * 4 + 2) * 8 + k] + x.w * aw[(f4 * 4 + 3) * 8 + k];
    }
    u[t] = softplusf(su + gb[k]);
    w[t] = sigmoidf_(sw + ab[k]);
}

// ---------------------------------------------------------------------------
// msg0 MFMA: M0-tile = A(128 ik x 512 j) * V(512 j x 64 f), bf16 mfma.
// DMA-staged V^T, swizzled LDS, fused d2/cos/A-gen. Grid 512 = 16b x 32 tiles.
// ---------------------------------------------------------------------------
__global__ __launch_bounds__(256)
void msg0_mfma(const u16* __restrict__ VT0, const float* __restrict__ C,
               const float* __restrict__ u0, const float* __restrict__ w0,
               u16* __restrict__ X0) {
    int b = blockIdx.x >> 5, i0 = (blockIdx.x & 31) * 16;
    int tid = threadIdx.x;
    int wv = tid >> 6, lane = tid & 63, quad = lane >> 4, l15 = lane & 15;

    __shared__ __align__(16) u16 s_vT[64 * 64];      // 8 KB  [f][j] swizzled
    __shared__ __align__(16) u16 s_A[128 * 64];      // 16 KB [ik][j] swizzled
    __shared__ __align__(16) float s_cj[64][4];      // x,y,z,l2
    __shared__ __align__(16) float s_ci[16][4];
    __shared__ __align__(16) float s_u[16][KK];
    __shared__ __align__(16) float s_w[16][KK];

    if (tid < 16) {
        const float* cp = C + ((size_t)b * 512 + i0 + tid) * 3;
        float x = cp[0], y = cp[1], z = cp[2];
        s_ci[tid][0] = x; s_ci[tid][1] = y; s_ci[tid][2] = z;
        s_ci[tid][3] = x * x + y * y + z * z;
    }
    if (tid < 128) {
        int i = tid >> 3, k = tid & 7;
        size_t idx = ((size_t)b * 512 + i0 + i) * KK + k;
        s_u[i][k] = u0[idx];
        s_w[i][k] = w0[idx];
    }

    f32x4 acc[2][4] = {};

    for (int j0 = 0; j0 < 512; j0 += 64) {
        __syncthreads();
        // stage V^T tile [64 f][64 j] via DMA (2 passes of 4KB)
#pragma unroll
        for (int p = 0; p < 2; p++) {
            int s = p * 256 + wv * 64 + lane;
            int f = s >> 3, op = s & 7;
            g2l16(VT0 + ((size_t)b * 64 + f) * 512 + j0 + ((op ^ (f & 7)) << 3),
                  (void*)(s_vT + (p * 256 + wv * 64) * 8));
        }
        if (tid < 64) {
            const float* cp = C + ((size_t)b * 512 + j0 + tid) * 3;
            float x = cp[0], y = cp[1], z = cp[2];
            s_cj[tid][0] = x; s_cj[tid][1] = y; s_cj[tid][2] = z;
            s_cj[tid][3] = x * x + y * y + z * z;
        }
        __syncthreads();
        // fused d2/cos/A-gen: thread -> (i = t*4+wv, j = lane), all 8 k
#pragma unroll
        for (int t = 0; t < 4; t++) {
            int i = t * 4 + wv, j = lane;
            float cix = s_ci[i][0], ciy = s_ci[i][1], ciz = s_ci[i][2], l2i = s_ci[i][3];
            float cjx = s_cj[j][0], cjy = s_cj[j][1], cjz = s_cj[j][2], l2j = s_cj[j][3];
            float dot = cix * cjx + ciy * cjy + ciz * cjz;
            float d2 = fabsf(l2i + l2j - 2.f * dot) + EPSF;
            float cs = dot / sqrtf((l2i + EPSF) * (l2j + EPSF));
            f32x4 u01 = *(const f32x4*)&s_u[i][0];
            f32x4 u23 = *(const f32x4*)&s_u[i][4];
            f32x4 w01 = *(const f32x4*)&s_w[i][0];
            f32x4 w23 = *(const f32x4*)&s_w[i][4];
#pragma unroll
            for (int k = 0; k < 4; k++) {
                float a = __expf(-d2 * u01[k]) * (w01[k] * cs + 1.f - w01[k]);
                int row = i * 8 + k;
                s_A[(row << 6) + (((j >> 3) ^ (row & 7)) << 3) + (j & 7)] = f2bf(a);
            }
#pragma unroll
            for (int k = 0; k < 4; k++) {
                float a = __expf(-d2 * u23[k]) * (w23[k] * cs + 1.f - w23[k]);
                int row = i * 8 + 4 + k;
                s_A[(row << 6) + (((j >> 3) ^ (row & 7)) << 3) + (j & 7)] = f2bf(a);
            }
        }
        __syncthreads();
#pragma unroll
        for (int ks = 0; ks < 2; ks++) {
            int o = ks * 4 + quad;
            bf16x8 a0 = *(const bf16x8*)&s_A[swz(wv * 32 + l15, o)];
            bf16x8 a1 = *(const bf16x8*)&s_A[swz(wv * 32 + 16 + l15, o)];
#pragma unroll
            for (int cf = 0; cf < 4; cf++) {
                bf16x8 bv = *(const bf16x8*)&s_vT[swz(cf * 16 + l15, o)];
                acc[0][cf] = MFMA_16x16x32(a0, bv, acc[0][cf]);
                acc[1][cf] = MFMA_16x16x32(a1, bv, acc[1][cf]);
            }
        }
    }
#pragma unroll
    for (int rf = 0; rf < 2; rf++)
#pragma unroll
        for (int cf = 0; cf < 4; cf++)
#pragma unroll
            for (int r = 0; r < 4; r++) {
                int arow = wv * 32 + rf * 16 + quad * 4 + r;
                int i = arow >> 3, k = arow & 7;
                X0[((size_t)b * 512 + i0 + i) * 576 + 64 + k * 64 + cf * 16 + l15] =
                    f2bf(acc[rf][cf][r]);
            }
}

// ---------------------------------------------------------------------------
// msg1 MFMA: A(128 ik x 256 j) * H(256 j x 128 f). Writes X1[:, 128:1152].
// Grid 256 = 16 b x 16 i-tiles.
// ---------------------------------------------------------------------------
__global__ __launch_bounds__(256)
void msg1_mfma(const u16* __restrict__ VT1, const float* __restrict__ C1,
               const float* __restrict__ u1, const float* __restrict__ w1,
               u16* __restrict__ X1) {
    int b = blockIdx.x >> 4, i0 = (blockIdx.x & 15) * 16;
    int tid = threadIdx.x;
    int wv = tid >> 6, lane = tid & 63, quad = lane >> 4, l15 = lane & 15;

    __shared__ __align__(16) u16 s_vT[128 * 64];     // 16 KB [f][j] swizzled
    __shared__ __align__(16) u16 s_A[128 * 64];      // 16 KB [ik][j] swizzled
    __shared__ __align__(16) float s_cj[64][4];
    __shared__ __align__(16) float s_ci[16][4];
    __shared__ __align__(16) float s_u[16][KK];
    __shared__ __align__(16) float s_w[16][KK];

    if (tid < 16) {
        const float* cp = C1 + ((size_t)b * 256 + i0 + tid) * 3;
        float x = cp[0], y = cp[1], z = cp[2];
        s_ci[tid][0] = x; s_ci[tid][1] = y; s_ci[tid][2] = z;
        s_ci[tid][3] = x * x + y * y + z * z;
    }
    if (tid < 128) {
        int i = tid >> 3, k = tid & 7;
        size_t idx = ((size_t)b * 256 + i0 + i) * KK + k;
        s_u[i][k] = u1[idx];
        s_w[i][k] = w1[idx];
    }

    f32x4 acc[2][8] = {};

    for (int j0 = 0; j0 < 256; j0 += 64) {
        __syncthreads();
        // stage H^T tile [128 f][64 j] via DMA (4 passes)
#pragma unroll
        for (int p = 0; p < 4; p++) {
            int s = p * 256 + wv * 64 + lane;
            int f = s >> 3, op = s & 7;
            g2l16(VT1 + ((size_t)b * 128 + f) * 256 + j0 + ((op ^ (f & 7)) << 3),
                  (void*)(s_vT + (p * 256 + wv * 64) * 8));
        }
        if (tid < 64) {
            const float* cp = C1 + ((size_t)b * 256 + j0 + tid) * 3;
            float x = cp[0], y = cp[1], z = cp[2];
            s_cj[tid][0] = x; s_cj[tid][1] = y; s_cj[tid][2] = z;
            s_cj[tid][3] = x * x + y * y + z * z;
        }
        __syncthreads();
#pragma unroll
        for (int t = 0; t < 4; t++) {
            int i = t * 4 + wv, j = lane;
            float cix = s_ci[i][0], ciy = s_ci[i][1], ciz = s_ci[i][2], l2i = s_ci[i][3];
            float cjx = s_cj[j][0], cjy = s_cj[j][1], cjz = s_cj[j][2], l2j = s_cj[j][3];
            float dot = cix * cjx + ciy * cjy + ciz * cjz;
            float d2 = fabsf(l2i + l2j - 2.f * dot) + EPSF;
            float cs = dot / sqrtf((l2i + EPSF) * (l2j + EPSF));
            f32x4 u01 = *(const f32x4*)&s_u[i][0];
            f32x4 u23 = *(const f32x4*)&s_u[i][4];
            f32x4 w01 = *(const f32x4*)&s_w[i][0];
            f32x4 w23 = *(const f32x4*)&s_w[i][4];
#pragma unroll
            for (int k = 0; k < 4; k++) {
                float a = __expf(-d2 * u01[k]) * (w01[k] * cs + 1.f - w01[k]);
                int row = i * 8 + k;
                s_A[(row << 6) + (((j >> 3) ^ (row & 7)) << 3) + (j & 7)] = f2bf(a);
            }
#pragma unroll
            for (int k = 0; k < 4; k++) {
                float a = __expf(-d2 * u23[k]) * (w23[k] * cs + 1.f - w23[k]);
                int row = i * 8 + 4 + k;
                s_A[(row << 6) + (((j >> 3) ^ (row & 7)) << 3) + (j & 7)] = f2bf(a);
            }
        }
        __syncthreads();
#pragma unroll
        for (int ks = 0; ks < 2; ks++) {
            int o = ks * 4 + quad;
            bf16x8 a0 = *(const bf16x8*)&s_A[swz(wv * 32 + l15, o)];
            bf16x8 a1 = *(const bf16x8*)&s_A[swz(wv * 32 + 16 + l15, o)];
#pragma unroll
            for (int cf = 0; cf < 8; cf++) {
                bf16x8 bv = *(const bf16x8*)&s_vT[swz(cf * 16 + l15, o)];
                acc[0][cf] = MFMA_16x16x32(a0, bv, acc[0][cf]);
                acc[1][cf] = MFMA_16x16x32(a1, bv, acc[1][cf]);
            }
        }
    }
#pragma unroll
    for (int rf = 0; rf < 2; rf++)
#pragma unroll
        for (int cf = 0; cf < 8; cf++)
#pragma unroll
            for (int r = 0; r < 4; r++) {
                int arow = wv * 32 + rf * 16 + quad * 4 + r;
                int i = arow >> 3, k = arow & 7;
                X1[((size_t)b * 256 + i0 + i) * 1152 + 128 + k * 128 + cf * 16 + l15] =
                    f2bf(acc[rf][cf][r]);
            }
}

// ---------------------------------------------------------------------------
// post0 MFMA GEMM: [8192 x 576] @ [576 x 128] -> tanh/bn -> pool.
// Tile 32x64, grid 512 = 256 rowtiles x 2 coltiles. DMA staging, swizzled.
// ---------------------------------------------------------------------------
__global__ __launch_bounds__(256)
void post0_mfma(const u16* __restrict__ X0, const u16* __restrict__ Wt,
                const float* __restrict__ bias, const float* __restrict__ bng,
                const float* __restrict__ bnb, float* __restrict__ H0p,
                u16* __restrict__ X1) {
    int row0 = (blockIdx.x >> 1) * 32, col0 = (blockIdx.x & 1) * 64;
    int tid = threadIdx.x;
    int wv = tid >> 6, lane = tid & 63, quad = lane >> 4, l15 = lane & 15;
    int rw = wv & 1, cw = wv >> 1;

    __shared__ __align__(16) u16 s_X[32 * 64];   // 4 KB
    __shared__ __align__(16) u16 s_W[64 * 64];   // 8 KB

    f32x4 acc[2] = {};

    for (int kc = 0; kc < 576; kc += 64) {
        __syncthreads();
        {   // X tile: 32 rows, 1 pass
            int s = wv * 64 + lane;
            int r = s >> 3, op = s & 7;
            g2l16(X0 + ((size_t)row0 + r) * 576 + kc + ((op ^ (r & 7)) << 3),
                  (void*)(s_X + (wv * 64) * 8));
        }
#pragma unroll
        for (int p = 0; p < 2; p++) {   // W tile: 64 rows, 2 passes
            int s = p * 256 + wv * 64 + lane;
            int c = s >> 3, op = s & 7;
            g2l16(Wt + ((size_t)col0 + c) * 576 + kc + ((op ^ (c & 7)) << 3),
                  (void*)(s_W + (p * 256 + wv * 64) * 8));
        }
        __syncthreads();
#pragma unroll
        for (int ks = 0; ks < 2; ks++) {
            int o = ks * 4 + quad;
            bf16x8 av = *(const bf16x8*)&s_X[swz(rw * 16 + l15, o)];
#pragma unroll
            for (int cf = 0; cf < 2; cf++) {
                bf16x8 bv = *(const bf16x8*)&s_W[swz(cw * 32 + cf * 16 + l15, o)];
                acc[cf] = MFMA_16x16x32(av, bv, acc[cf]);
            }
        }
    }
#pragma unroll
    for (int cf = 0; cf < 2; cf++) {
        int col = col0 + cw * 32 + cf * 16 + l15;
        float bs = bias[col], gg = bng[col], bb = bnb[col];
        float h0 = gg * tanhf(acc[cf][0] + bs) + bb;
        float h1 = gg * tanhf(acc[cf][1] + bs) + bb;
        float h2 = gg * tanhf(acc[cf][2] + bs) + bb;
        float h3 = gg * tanhf(acc[cf][3] + bs) + bb;
        float p0 = 0.5f * (h0 + h1), p1 = 0.5f * (h2 + h3);
        size_t pr = (size_t)(row0 >> 1) + rw * 8 + quad * 2;
        H0p[pr * 128 + col] = p0;
        H0p[(pr + 1) * 128 + col] = p1;
        X1[pr * 1152 + col] = f2bf(p0);
        X1[(pr + 1) * 1152 + col] = f2bf(p1);
    }
}

// ---------------------------------------------------------------------------
// post1 MFMA GEMM: [4096 x 1152] @ [1152 x 256] -> tanh/bn -> pool.
// Tile 32x64, grid 512 = 128 rowtiles x 4 coltiles. DMA staging, swizzled.
// ---------------------------------------------------------------------------
__global__ __launch_bounds__(256)
void post1_mfma(const u16* __restrict__ X1, const u16* __restrict__ Wt,
                const float* __restrict__ bias, const float* __restrict__ bng,
                const float* __restrict__ bnb, float* __restrict__ H1p) {
    int row0 = (blockIdx.x >> 2) * 32, col0 = (blockIdx.x & 3) * 64;
    int tid = threadIdx.x;
    int wv = tid >> 6, lane = tid & 63, quad = lane >> 4, l15 = lane & 15;
    int rw = wv & 1, cw = wv >> 1;

    __shared__ __align__(16) u16 s_X[32 * 64];
    __shared__ __align__(16) u16 s_W[64 * 64];

    f32x4 acc[2] = {};

    for (int kc = 0; kc < 1152; kc += 64) {
        __syncthreads();
        {
            int s = wv * 64 + lane;
            int r = s >> 3, op = s & 7;
            g2l16(X1 + ((size_t)row0 + r) * 1152 + kc + ((op ^ (r & 7)) << 3),
                  (void*)(s_X + (wv * 64) * 8));
        }
#pragma unroll
        for (int p = 0; p < 2; p++) {
            int s = p * 256 + wv * 64 + lane;
            int c = s >> 3, op = s & 7;
            g2l16(Wt + ((size_t)col0 + c) * 1152 + kc + ((op ^ (c & 7)) << 3),
                  (void*)(s_W + (p * 256 + wv * 64) * 8));
        }
        __syncthreads();
#pragma unroll
        for (int ks = 0; ks < 2; ks++) {
            int o = ks * 4 + quad;
            bf16x8 av = *(const bf16x8*)&s_X[swz(rw * 16 + l15, o)];
#pragma unroll
            for (int cf = 0; cf < 2; cf++) {
                bf16x8 bv = *(const bf16x8*)&s_W[swz(cw * 32 + cf * 16 + l15, o)];
                acc[cf] = MFMA_16x16x32(av, bv, acc[cf]);
            }
        }
    }
#pragma unroll
    for (int cf = 0; cf < 2; cf++) {
        int col = col0 + cw * 32 + cf * 16 + l15;
        float bs = bias[col], gg = bng[col], bb = bnb[col];
        float h0 = gg * tanhf(acc[cf][0] + bs) + bb;
        float h1 = gg * tanhf(acc[cf][1] + bs) + bb;
        float h2 = gg * tanhf(acc[cf][2] + bs) + bb;
        float h3 = gg * tanhf(acc[cf][3] + bs) + bb;
        float p0 = 0.5f * (h0 + h1), p1 = 0.5f * (h2 + h3);
        size_t pr = (size_t)(row0 >> 1) + rw * 8 + quad * 2;
        H1p[pr * 256 + col] = p0;
        H1p[(pr + 1) * 256 + col] = p1;
    }
}

// ---------------------------------------------------------------------------
// Pool coords: C1[b,i,:] = 0.5*(C[b,2i,:] + C[b,2i+1,:])
// ---------------------------------------------------------------------------
__global__ void c1pool_kernel(const float* __restrict__ C, float* __restrict__ C1) {
    int o = blockIdx.x * 256 + threadIdx.x;
    if (o >= 16 * 256 * 3) return;
    int d = o % 3;
    int node = o / 3;
    int b = node >> 8, i = node & 255;
    size_t src = ((size_t)(b * 512 + 2 * i)) * 3 + d;
    C1[o] = 0.5f * (C[src] + C[src + 3]);
}

// ---------------------------------------------------------------------------
// FC split-K v2: grid 512 = 4 col-splits x 128 k-splits (m-chunks of 256).
// Flat slice staged to LDS (xT swizzled); W streamed 8 float4 in flight.
// P[ks][16][512] partials, reduced by fc_reduce.
// ---------------------------------------------------------------------------
__global__ __launch_bounds__(256)
void fc_partial_kernel(const float* __restrict__ Flat, const float* __restrict__ W,
                       float* __restrict__ P) {
    int cs = blockIdx.x & 3, ks = blockIdx.x >> 2;
    int m0 = ks * 256;
    int c4 = threadIdx.x & 31;          // col float4 within this 128-col slice
    int msub = threadIdx.x >> 5;        // 0..7 -> 32 m-rows each

    __shared__ __align__(16) float xT[256][16];   // 16 KB, b-groups XOR-swizzled

    // stage Flat [16 b][256 m] -> xT[m][swz(b)]
#pragma unroll
    for (int q = 0; q < 16; q++) {
        int idx = q * 256 + threadIdx.x;
        int b = idx >> 8, mm = idx & 255;
        int bg = (b >> 2) ^ (mm & 3);
        xT[mm][(bg << 2) + (b & 3)] = Flat[(size_t)b * 32768 + m0 + mm];
    }
    __syncthreads();

    const float4* W4 = (const float4*)W;
    float4 acc[16] = {};   // [b]

    for (int h = 0; h < 4; h++) {                  // 4 batches of 8 m-rows
        float4 wbuf[8];
#pragma unroll
        for (int i = 0; i < 8; i++) {
            int mm = msub * 32 + h * 8 + i;
            wbuf[i] = W4[(size_t)(m0 + mm) * 128 + cs * 32 + c4];
        }
#pragma unroll
        for (int i = 0; i < 8; i++) {
            int mm = msub * 32 + h * 8 + i;
#pragma unroll
            for (int bg = 0; bg < 4; bg++) {
                float4 xv = *(const float4*)&xT[mm][((bg ^ (mm & 3)) << 2)];
                acc[bg * 4 + 0].x += xv.x * wbuf[i].x; acc[bg * 4 + 0].y += xv.x * wbuf[i].y;
                acc[bg * 4 + 0].z += xv.x * wbuf[i].z; acc[bg * 4 + 0].w += xv.x * wbuf[i].w;
                acc[bg * 4 + 1].x += xv.y * wbuf[i].x; acc[bg * 4 + 1].y += xv.y * wbuf[i].y;
                acc[bg * 4 + 1].z += xv.y * wbuf[i].z; acc[bg * 4 + 1].w += xv.y * wbuf[i].w;
                acc[bg * 4 + 2].x += xv.z * wbuf[i].x; acc[bg * 4 + 2].y += xv.z * wbuf[i].y;
                acc[bg * 4 + 2].z += xv.z * wbuf[i].z; acc[bg * 4 + 2].w += xv.z * wbuf[i].w;
                acc[bg * 4 + 3].x += xv.w * wbuf[i].x; acc[bg * 4 + 3].y += xv.w * wbuf[i].y;
                acc[bg * 4 + 3].z += xv.w * wbuf[i].z; acc[bg * 4 + 3].w += xv.w * wbuf[i].w;
            }
        }
    }
    // cross-thread partial reduce over msub happens in fc_reduce (8 msub kept
    // separate would cost 8x P traffic) -> instead reduce msub via LDS here.
    __syncthreads();
    // reuse xT as reduction scratch: 8 msub x 32 c4 x ... too small; do atomic-free
    // tree: msub pairs via LDS in 4 steps over a [256][16] float view.
    // Simpler: each msub writes partial to LDS and msub 0 accumulates.
    __shared__ __align__(16) float red[8][32][4];  // [msub][c4][4 cols] per b-slice
#pragma unroll
    for (int b = 0; b < 16; b++) {
        red[msub][c4][0] = acc[b].x; red[msub][c4][1] = acc[b].y;
        red[msub][c4][2] = acc[b].z; red[msub][c4][3] = acc[b].w;
        __syncthreads();
        if (msub == 0) {
            float4 s = make_float4(0.f, 0.f, 0.f, 0.f);
#pragma unroll
            for (int m = 0; m < 8; m++) {
                s.x += red[m][c4][0]; s.y += red[m][c4][1];
                s.z += red[m][c4][2]; s.w += red[m][c4][3];
            }
            *(float4*)&P[((size_t)ks * 16 + b) * 512 + cs * 128 + c4 * 4] = s;
        }
        __syncthreads();
    }
}

__global__ void fc_reduce_kernel(const float* __restrict__ P, const float* __restrict__ fcb,
                                 float* __restrict__ out) {
    int idx = blockIdx.x * 256 + threadIdx.x;   // 8192 outputs
    float s0 = 0.f, s1 = 0.f;
#pragma unroll 8
    for (int ks = 0; ks < 128; ks += 2) {
        s0 += P[(size_t)ks * 8192 + idx];
        s1 += P[(size_t)(ks + 1) * 8192 + idx];
    }
    float s = s0 + s1 + fcb[idx & 511];
    out[idx] = 1.f / (1.f + expf(-s));
}

// ---------------------------------------------------------------------------
extern "C" void kernel_launch(void* const* d_in, const int* in_sizes, int n_in,
                              void* d_out, int out_size, void* d_ws, size_t ws_size,
                              hipStream_t stream) {
    const float* V     = (const float*)d_in[0];
    const float* C     = (const float*)d_in[1];
    const float* gk_w0 = (const float*)d_in[2];
    const float* gk_b0 = (const float*)d_in[3];
    const float* ac_w0 = (const float*)d_in[4];
    const float* ac_b0 = (const float*)d_in[5];
    const float* gc_w0 = (const float*)d_in[6];
    const float* gc_b0 = (const float*)d_in[7];
    const float* bn_g0 = (const float*)d_in[8];
    const float* bn_b0 = (const float*)d_in[9];
    const float* gk_w1 = (const float*)d_in[10];
    const float* gk_b1 = (const float*)d_in[11];
    const float* ac_w1 = (const float*)d_in[12];
    const float* ac_b1 = (const float*)d_in[13];
    const float* gc_w1 = (const float*)d_in[14];
    const float* gc_b1 = (const float*)d_in[15];
    const float* bn_g1 = (const float*)d_in[16];
    const float* bn_b1 = (const float*)d_in[17];
    const float* fc_w  = (const float*)d_in[18];
    const float* fc_b  = (const float*)d_in[19];
    float* out = (float*)d_out;

    float* u0  = (float*)d_ws;        // 65536
    float* w0  = u0 + 65536;          // 65536
    float* u1  = w0 + 65536;          // 32768
    float* w1  = u1 + 32768;          // 32768
    float* C1  = w1 + 32768;          // 12288
    float* H0p = C1 + 12288;          // 524288
    float* H1p = H0p + 524288;        // 524288
    float* Pad = H1p + 524288;        // 262144 (spare)
    u16* X0  = (u16*)(Pad + 262144);  // 4718592  [8192][576]
    u16* X1  = X0 + 4718592;          // 4718592  [4096][1152]
    u16* VT0 = X1 + 4718592;          // 524288   [16][64][512]; aliased as VT1
    u16* Wt0 = VT0 + 524288;          // 73728    [128][576]
    u16* Wt1 = Wt0 + 73728;           // 294912   [256][1152]
    u16* VT1 = VT0;  // msg0 finishes with VT0 before t_h0p writes (stream order)
    // P partials (128*16*512 = 1M floats = 4MB) alias X0 (dead after post0)
    float* P = (float*)X0;

    prep_kernel<<<346, 256, 0, stream>>>(V, gc_w0, gc_w1, VT0, Wt0, Wt1, X0);
    uw_kernel<64><<<256, 256, 0, stream>>>(V, gk_w0, gk_b0, ac_w0, ac_b0, u0, w0, 8192);
    msg0_mfma<<<512, 256, 0, stream>>>(VT0, C, u0, w0, X0);
    post0_mfma<<<512, 256, 0, stream>>>(X0, Wt0, gc_b0, bn_g0, bn_b0, H0p, X1);
    c1pool_kernel<<<48, 256, 0, stream>>>(C, C1);
    t_h0p_kernel<<<128, 256, 0, stream>>>(H0p, VT1);
    uw_kernel<128><<<128, 256, 0, stream>>>(H0p, gk_w1, gk_b1, ac_w1, ac_b1, u1, w1, 4096);
    msg1_mfma<<<256, 256, 0, stream>>>(VT1, C1, u1, w1, X1);
    post1_mfma<<<512, 256, 0, stream>>>(X1, Wt1, gc_b1, bn_g1, bn_b1, H1p);
    fc_partial_kernel<<<512, 256, 0, stream>>>(H1p, fc_w, P);
    fc_reduce_kernel<<<32, 256, 0, stream>>>(P, fc_b, out);
}

// Round 5
// 224.333 us; speedup vs baseline: 2.6606x; 1.0169x over previous
//
#include <hip/hip_runtime.h>
#include <math.h>

#define KK 8
#define EPSF 1e-9f

typedef unsigned int   uint32;
typedef unsigned short u16;
typedef __attribute__((ext_vector_type(8))) short bf16x8;
typedef __attribute__((ext_vector_type(4))) float f32x4;

#define MFMA_16x16x32(a, b, c) __builtin_amdgcn_mfma_f32_16x16x32_bf16(a, b, c, 0, 0, 0)

typedef __attribute__((address_space(1))) const unsigned int glob_cu32;
typedef __attribute__((address_space(3))) unsigned int lds_u32;
// async global->LDS DMA, 16B per lane; LDS dest = wave-uniform base + lane*16
__device__ __forceinline__ void g2l16(const void* gsrc, void* ldst) {
    __builtin_amdgcn_global_load_lds((glob_cu32*)gsrc, (lds_u32*)ldst, 16, 0, 0);
}

// swizzled ushort index of logical octet o (8 bf16) in a [row][64] LDS tile
__device__ __forceinline__ int swz(int row, int o) {
    return (row << 6) + (((o) ^ (row & 7)) << 3);
}

__device__ __forceinline__ float softplusf(float x) {
    return x > 0.0f ? x + log1pf(expf(-x)) : log1pf(expf(x));
}
__device__ __forceinline__ float sigmoidf_(float x) {
    return 1.0f / (1.0f + expf(-x));
}
// fp32 -> bf16 round-to-nearest-even
__device__ __forceinline__ u16 f2bf(float f) {
    union { float f; uint32 u; } v; v.f = f;
    uint32 u = v.u;
    return (u16)((u + 0x7FFFu + ((u >> 16) & 1u)) >> 16);
}

// ---------------------------------------------------------------------------
// prep: V->VT0 bf16 [16][64][512] (transposed), gc_w0->Wt0 bf16 [128][576],
//       gc_w1->Wt1 bf16 [256][1152], V->X0[:, :64] bf16 (straight).
// ---------------------------------------------------------------------------
__global__ __launch_bounds__(256)
void prep_kernel(const float* __restrict__ V, const float* __restrict__ W0,
                 const float* __restrict__ W1, u16* __restrict__ VT0,
                 u16* __restrict__ Wt0, u16* __restrict__ Wt1,
                 u16* __restrict__ X0) {
    __shared__ float s[64][65];
    int blk = blockIdx.x, tid = threadIdx.x;
    if (blk < 128) {            // V [16][512][64] -> VT0 [16][64][512]
        int b = blk >> 3, rt = blk & 7;
#pragma unroll
        for (int t = 0; t < 16; t++) {
            int idx = t * 256 + tid; int r = idx >> 6, c = idx & 63;
            s[r][c] = V[((size_t)b * 512 + rt * 64 + r) * 64 + c];
        }
        __syncthreads();
#pragma unroll
        for (int t = 0; t < 16; t++) {
            int idx = t * 256 + tid; int f = idx >> 6, j = idx & 63;
            VT0[((size_t)b * 64 + f) * 512 + rt * 64 + j] = f2bf(s[j][f]);
        }
    } else if (blk < 146) {     // W0 [576][128] -> Wt0 [128][576]
        int t0 = blk - 128; int rt = t0 >> 1, ct = t0 & 1;
#pragma unroll
        for (int t = 0; t < 16; t++) {
            int idx = t * 256 + tid; int r = idx >> 6, c = idx & 63;
            s[r][c] = W0[((size_t)rt * 64 + r) * 128 + ct * 64 + c];
        }
        __syncthreads();
#pragma unroll
        for (int t = 0; t < 16; t++) {
            int idx = t * 256 + tid; int f = idx >> 6, j = idx & 63;
            Wt0[((size_t)ct * 64 + f) * 576 + rt * 64 + j] = f2bf(s[j][f]);
        }
    } else if (blk < 218) {     // W1 [1152][256] -> Wt1 [256][1152]
        int t0 = blk - 146; int rt = t0 >> 2, ct = t0 & 3;
#pragma unroll
        for (int t = 0; t < 16; t++) {
            int idx = t * 256 + tid; int r = idx >> 6, c = idx & 63;
            s[r][c] = W1[((size_t)rt * 64 + r) * 256 + ct * 64 + c];
        }
        __syncthreads();
#pragma unroll
        for (int t = 0; t < 16; t++) {
            int idx = t * 256 + tid; int f = idx >> 6, j = idx & 63;
            Wt1[((size_t)ct * 64 + f) * 1152 + rt * 64 + j] = f2bf(s[j][f]);
        }
    } else {                    // V flat -> X0[:, 0:64] bf16
        int t0 = blk - 218;
#pragma unroll
        for (int q = 0; q < 16; q++) {
            int e = t0 * 4096 + q * 256 + tid;
            int row = e >> 6, c = e & 63;
            X0[(size_t)row * 576 + c] = f2bf(V[e]);
        }
    }
}

// ---------------------------------------------------------------------------
// transpose H0p [16][256][128] fp32 -> VT1 [16][128][256] bf16
// ---------------------------------------------------------------------------
__global__ __launch_bounds__(256)
void t_h0p_kernel(const float* __restrict__ H0p, u16* __restrict__ VT1) {
    __shared__ float s[64][65];
    int blk = blockIdx.x, tid = threadIdx.x;
    int b = blk >> 3, rt = (blk >> 1) & 3, ct = blk & 1;
#pragma unroll
    for (int t = 0; t < 16; t++) {
        int idx = t * 256 + tid; int r = idx >> 6, c = idx & 63;
        s[r][c] = H0p[((size_t)b * 256 + rt * 64 + r) * 128 + ct * 64 + c];
    }
    __syncthreads();
#pragma unroll
    for (int t = 0; t < 16; t++) {
        int idx = t * 256 + tid; int f = idx >> 6, j = idx & 63;
        VT1[((size_t)b * 128 + ct * 64 + f) * 256 + rt * 64 + j] = f2bf(s[j][f]);
    }
}

// ---------------------------------------------------------------------------
// msg0 MFMA (fused uw0): per block computes u/w for its 16 i-rows, then
// M0-tile = A(128 ik x 512 j) * V(512 j x 64 f). Grid 512 = 16b x 32 tiles.
// 2 barriers per K-iter (j-coords in registers).
// ---------------------------------------------------------------------------
__global__ __launch_bounds__(256)
void msg0_mfma(const u16* __restrict__ VT0, const float* __restrict__ C,
               const float* __restrict__ V,
               const float* __restrict__ gw, const float* __restrict__ gb,
               const float* __restrict__ aw, const float* __restrict__ ab,
               u16* __restrict__ X0) {
    int b = blockIdx.x >> 5, i0 = (blockIdx.x & 31) * 16;
    int tid = threadIdx.x;
    int wv = tid >> 6, lane = tid & 63, quad = lane >> 4, l15 = lane & 15;

    __shared__ __align__(16) u16 s_vT[64 * 64];      // 8 KB  [f][j] swizzled
    __shared__ __align__(16) u16 s_A[128 * 64];      // 16 KB [ik][j] swizzled
    __shared__ __align__(16) float s_ci[16][4];
    __shared__ __align__(16) float s_u[16][KK];
    __shared__ __align__(16) float s_w[16][KK];

    // fused uw: tid<128 -> u for (i,k), tid>=128 -> w for (i,k)
    {
        int t = tid & 127;
        int i = t >> 3, k = t & 7;
        const float4* xr = (const float4*)(V + ((size_t)b * 512 + i0 + i) * 64);
        const float* wm = (tid < 128) ? gw : aw;
        float s = 0.f;
#pragma unroll
        for (int f4 = 0; f4 < 16; f4++) {
            float4 x = xr[f4];
            s += x.x * wm[(f4 * 4 + 0) * 8 + k] + x.y * wm[(f4 * 4 + 1) * 8 + k]
               + x.z * wm[(f4 * 4 + 2) * 8 + k] + x.w * wm[(f4 * 4 + 3) * 8 + k];
        }
        if (tid < 128) s_u[i][k] = softplusf(s + gb[k]);
        else           s_w[i][k] = sigmoidf_(s + ab[k]);
    }
    if (tid < 16) {
        const float* cp = C + ((size_t)b * 512 + i0 + tid) * 3;
        float x = cp[0], y = cp[1], z = cp[2];
        s_ci[tid][0] = x; s_ci[tid][1] = y; s_ci[tid][2] = z;
        s_ci[tid][3] = x * x + y * y + z * z;
    }
    __syncthreads();

    f32x4 acc[2][4] = {};

    for (int j0 = 0; j0 < 512; j0 += 64) {
        // per-thread j coords in registers (thread j = lane)
        const float* cp = C + ((size_t)b * 512 + j0 + lane) * 3;
        float cjx = cp[0], cjy = cp[1], cjz = cp[2];
        float l2j = cjx * cjx + cjy * cjy + cjz * cjz;
        __syncthreads();               // prev-iter MFMA LDS reads drained
#pragma unroll
        for (int p = 0; p < 2; p++) {  // DMA V^T tile [64 f][64 j]
            int s = p * 256 + wv * 64 + lane;
            int f = s >> 3, op = s & 7;
            g2l16(VT0 + ((size_t)b * 64 + f) * 512 + j0 + ((op ^ (f & 7)) << 3),
                  (void*)(s_vT + (p * 256 + wv * 64) * 8));
        }
        // A-gen: thread -> (i = t*4+wv, j = lane), all 8 k
#pragma unroll
        for (int t = 0; t < 4; t++) {
            int i = t * 4 + wv, j = lane;
            float dot = s_ci[i][0] * cjx + s_ci[i][1] * cjy + s_ci[i][2] * cjz;
            float d2 = fabsf(s_ci[i][3] + l2j - 2.f * dot) + EPSF;
            float cs = dot / sqrtf((s_ci[i][3] + EPSF) * (l2j + EPSF));
            f32x4 u01 = *(const f32x4*)&s_u[i][0];
            f32x4 u23 = *(const f32x4*)&s_u[i][4];
            f32x4 w01 = *(const f32x4*)&s_w[i][0];
            f32x4 w23 = *(const f32x4*)&s_w[i][4];
#pragma unroll
            for (int k = 0; k < 4; k++) {
                float a = __expf(-d2 * u01[k]) * (w01[k] * cs + 1.f - w01[k]);
                int row = i * 8 + k;
                s_A[(row << 6) + (((j >> 3) ^ (row & 7)) << 3) + (j & 7)] = f2bf(a);
            }
#pragma unroll
            for (int k = 0; k < 4; k++) {
                float a = __expf(-d2 * u23[k]) * (w23[k] * cs + 1.f - w23[k]);
                int row = i * 8 + 4 + k;
                s_A[(row << 6) + (((j >> 3) ^ (row & 7)) << 3) + (j & 7)] = f2bf(a);
            }
        }
        __syncthreads();               // DMA + A-writes visible
#pragma unroll
        for (int ks = 0; ks < 2; ks++) {
            int o = ks * 4 + quad;
            bf16x8 a0 = *(const bf16x8*)&s_A[swz(wv * 32 + l15, o)];
            bf16x8 a1 = *(const bf16x8*)&s_A[swz(wv * 32 + 16 + l15, o)];
#pragma unroll
            for (int cf = 0; cf < 4; cf++) {
                bf16x8 bv = *(const bf16x8*)&s_vT[swz(cf * 16 + l15, o)];
                acc[0][cf] = MFMA_16x16x32(a0, bv, acc[0][cf]);
                acc[1][cf] = MFMA_16x16x32(a1, bv, acc[1][cf]);
            }
        }
    }
#pragma unroll
    for (int rf = 0; rf < 2; rf++)
#pragma unroll
        for (int cf = 0; cf < 4; cf++)
#pragma unroll
            for (int r = 0; r < 4; r++) {
                int arow = wv * 32 + rf * 16 + quad * 4 + r;
                int i = arow >> 3, k = arow & 7;
                X0[((size_t)b * 512 + i0 + i) * 576 + 64 + k * 64 + cf * 16 + l15] =
                    f2bf(acc[rf][cf][r]);
            }
}

// ---------------------------------------------------------------------------
// msg1 MFMA (fused uw1 + inline C-pooling): A(128 ik x 256 j) * H(256 j x 64 f-half).
// Grid 512 = 16 b x 16 i-tiles x 2 f-halves. Writes X1[:, 128:1152].
// ---------------------------------------------------------------------------
__global__ __launch_bounds__(256)
void msg1_mfma(const u16* __restrict__ VT1, const float* __restrict__ C,
               const float* __restrict__ H0p,
               const float* __restrict__ gw, const float* __restrict__ gb,
               const float* __restrict__ aw, const float* __restrict__ ab,
               u16* __restrict__ X1) {
    int b = blockIdx.x >> 5, i0 = ((blockIdx.x >> 1) & 15) * 16, fh = blockIdx.x & 1;
    int tid = threadIdx.x;
    int wv = tid >> 6, lane = tid & 63, quad = lane >> 4, l15 = lane & 15;

    __shared__ __align__(16) u16 s_vT[64 * 64];      // 8 KB (this f-half)
    __shared__ __align__(16) u16 s_A[128 * 64];      // 16 KB
    __shared__ __align__(16) float s_ci[16][4];
    __shared__ __align__(16) float s_u[16][KK];
    __shared__ __align__(16) float s_w[16][KK];

    // fused uw over H0p rows (F=128)
    {
        int t = tid & 127;
        int i = t >> 3, k = t & 7;
        const float4* xr = (const float4*)(H0p + ((size_t)b * 256 + i0 + i) * 128);
        const float* wm = (tid < 128) ? gw : aw;
        float s = 0.f;
#pragma unroll
        for (int f4 = 0; f4 < 32; f4++) {
            float4 x = xr[f4];
            s += x.x * wm[(f4 * 4 + 0) * 8 + k] + x.y * wm[(f4 * 4 + 1) * 8 + k]
               + x.z * wm[(f4 * 4 + 2) * 8 + k] + x.w * wm[(f4 * 4 + 3) * 8 + k];
        }
        if (tid < 128) s_u[i][k] = softplusf(s + gb[k]);
        else           s_w[i][k] = sigmoidf_(s + ab[k]);
    }
    if (tid < 16) {
        // pooled coords: C1[i] = 0.5*(C[2i] + C[2i+1])
        const float* cp = C + ((size_t)b * 512 + 2 * (i0 + tid)) * 3;
        float x = 0.5f * (cp[0] + cp[3]);
        float y = 0.5f * (cp[1] + cp[4]);
        float z = 0.5f * (cp[2] + cp[5]);
        s_ci[tid][0] = x; s_ci[tid][1] = y; s_ci[tid][2] = z;
        s_ci[tid][3] = x * x + y * y + z * z;
    }
    __syncthreads();

    f32x4 acc[2][4] = {};

    for (int j0 = 0; j0 < 256; j0 += 64) {
        const float* cp = C + ((size_t)b * 512 + 2 * (j0 + lane)) * 3;
        float cjx = 0.5f * (cp[0] + cp[3]);
        float cjy = 0.5f * (cp[1] + cp[4]);
        float cjz = 0.5f * (cp[2] + cp[5]);
        float l2j = cjx * cjx + cjy * cjy + cjz * cjz;
        __syncthreads();
#pragma unroll
        for (int p = 0; p < 2; p++) {  // DMA H^T half-tile [64 f][64 j]
            int s = p * 256 + wv * 64 + lane;
            int f = s >> 3, op = s & 7;
            g2l16(VT1 + ((size_t)b * 128 + fh * 64 + f) * 256 + j0 + ((op ^ (f & 7)) << 3),
                  (void*)(s_vT + (p * 256 + wv * 64) * 8));
        }
#pragma unroll
        for (int t = 0; t < 4; t++) {
            int i = t * 4 + wv, j = lane;
            float dot = s_ci[i][0] * cjx + s_ci[i][1] * cjy + s_ci[i][2] * cjz;
            float d2 = fabsf(s_ci[i][3] + l2j - 2.f * dot) + EPSF;
            float cs = dot / sqrtf((s_ci[i][3] + EPSF) * (l2j + EPSF));
            f32x4 u01 = *(const f32x4*)&s_u[i][0];
            f32x4 u23 = *(const f32x4*)&s_u[i][4];
            f32x4 w01 = *(const f32x4*)&s_w[i][0];
            f32x4 w23 = *(const f32x4*)&s_w[i][4];
#pragma unroll
            for (int k = 0; k < 4; k++) {
                float a = __expf(-d2 * u01[k]) * (w01[k] * cs + 1.f - w01[k]);
                int row = i * 8 + k;
                s_A[(row << 6) + (((j >> 3) ^ (row & 7)) << 3) + (j & 7)] = f2bf(a);
            }
#pragma unroll
            for (int k = 0; k < 4; k++) {
                float a = __expf(-d2 * u23[k]) * (w23[k] * cs + 1.f - w23[k]);
                int row = i * 8 + 4 + k;
                s_A[(row << 6) + (((j >> 3) ^ (row & 7)) << 3) + (j & 7)] = f2bf(a);
            }
        }
        __syncthreads();
#pragma unroll
        for (int ks = 0; ks < 2; ks++) {
            int o = ks * 4 + quad;
            bf16x8 a0 = *(const bf16x8*)&s_A[swz(wv * 32 + l15, o)];
            bf16x8 a1 = *(const bf16x8*)&s_A[swz(wv * 32 + 16 + l15, o)];
#pragma unroll
            for (int cf = 0; cf < 4; cf++) {
                bf16x8 bv = *(const bf16x8*)&s_vT[swz(cf * 16 + l15, o)];
                acc[0][cf] = MFMA_16x16x32(a0, bv, acc[0][cf]);
                acc[1][cf] = MFMA_16x16x32(a1, bv, acc[1][cf]);
            }
        }
    }
#pragma unroll
    for (int rf = 0; rf < 2; rf++)
#pragma unroll
        for (int cf = 0; cf < 4; cf++)
#pragma unroll
            for (int r = 0; r < 4; r++) {
                int arow = wv * 32 + rf * 16 + quad * 4 + r;
                int i = arow >> 3, k = arow & 7;
                X1[((size_t)b * 256 + i0 + i) * 1152 + 128 + k * 128 + fh * 64 + cf * 16 + l15] =
                    f2bf(acc[rf][cf][r]);
            }
}

// ---------------------------------------------------------------------------
// post0 MFMA GEMM: [8192 x 576] @ [576 x 128] -> tanh/bn -> pool.
// Tile 32x64, grid 512 = 256 rowtiles x 2 coltiles. DMA staging, swizzled.
// ---------------------------------------------------------------------------
__global__ __launch_bounds__(256)
void post0_mfma(const u16* __restrict__ X0, const u16* __restrict__ Wt,
                const float* __restrict__ bias, const float* __restrict__ bng,
                const float* __restrict__ bnb, float* __restrict__ H0p,
                u16* __restrict__ X1) {
    int row0 = (blockIdx.x >> 1) * 32, col0 = (blockIdx.x & 1) * 64;
    int tid = threadIdx.x;
    int wv = tid >> 6, lane = tid & 63, quad = lane >> 4, l15 = lane & 15;
    int rw = wv & 1, cw = wv >> 1;

    __shared__ __align__(16) u16 s_X[32 * 64];   // 4 KB
    __shared__ __align__(16) u16 s_W[64 * 64];   // 8 KB

    f32x4 acc[2] = {};

    for (int kc = 0; kc < 576; kc += 64) {
        __syncthreads();
        {   // X tile: 32 rows, 1 pass
            int s = wv * 64 + lane;
            int r = s >> 3, op = s & 7;
            g2l16(X0 + ((size_t)row0 + r) * 576 + kc + ((op ^ (r & 7)) << 3),
                  (void*)(s_X + (wv * 64) * 8));
        }
#pragma unroll
        for (int p = 0; p < 2; p++) {   // W tile: 64 rows, 2 passes
            int s = p * 256 + wv * 64 + lane;
            int c = s >> 3, op = s & 7;
            g2l16(Wt + ((size_t)col0 + c) * 576 + kc + ((op ^ (c & 7)) << 3),
                  (void*)(s_W + (p * 256 + wv * 64) * 8));
        }
        __syncthreads();
#pragma unroll
        for (int ks = 0; ks < 2; ks++) {
            int o = ks * 4 + quad;
            bf16x8 av = *(const bf16x8*)&s_X[swz(rw * 16 + l15, o)];
#pragma unroll
            for (int cf = 0; cf < 2; cf++) {
                bf16x8 bv = *(const bf16x8*)&s_W[swz(cw * 32 + cf * 16 + l15, o)];
                acc[cf] = MFMA_16x16x32(av, bv, acc[cf]);
            }
        }
    }
#pragma unroll
    for (int cf = 0; cf < 2; cf++) {
        int col = col0 + cw * 32 + cf * 16 + l15;
        float bs = bias[col], gg = bng[col], bb = bnb[col];
        float h0 = gg * tanhf(acc[cf][0] + bs) + bb;
        float h1 = gg * tanhf(acc[cf][1] + bs) + bb;
        float h2 = gg * tanhf(acc[cf][2] + bs) + bb;
        float h3 = gg * tanhf(acc[cf][3] + bs) + bb;
        float p0 = 0.5f * (h0 + h1), p1 = 0.5f * (h2 + h3);
        size_t pr = (size_t)(row0 >> 1) + rw * 8 + quad * 2;
        H0p[pr * 128 + col] = p0;
        H0p[(pr + 1) * 128 + col] = p1;
        X1[pr * 1152 + col] = f2bf(p0);
        X1[(pr + 1) * 1152 + col] = f2bf(p1);
    }
}

// ---------------------------------------------------------------------------
// post1 MFMA GEMM: [4096 x 1152] @ [1152 x 256] -> tanh/bn -> pool.
// Tile 32x64, grid 512 = 128 rowtiles x 4 coltiles. DMA staging, swizzled.
// ---------------------------------------------------------------------------
__global__ __launch_bounds__(256)
void post1_mfma(const u16* __restrict__ X1, const u16* __restrict__ Wt,
                const float* __restrict__ bias, const float* __restrict__ bng,
                const float* __restrict__ bnb, float* __restrict__ H1p) {
    int row0 = (blockIdx.x >> 2) * 32, col0 = (blockIdx.x & 3) * 64;
    int tid = threadIdx.x;
    int wv = tid >> 6, lane = tid & 63, quad = lane >> 4, l15 = lane & 15;
    int rw = wv & 1, cw = wv >> 1;

    __shared__ __align__(16) u16 s_X[32 * 64];
    __shared__ __align__(16) u16 s_W[64 * 64];

    f32x4 acc[2] = {};

    for (int kc = 0; kc < 1152; kc += 64) {
        __syncthreads();
        {
            int s = wv * 64 + lane;
            int r = s >> 3, op = s & 7;
            g2l16(X1 + ((size_t)row0 + r) * 1152 + kc + ((op ^ (r & 7)) << 3),
                  (void*)(s_X + (wv * 64) * 8));
        }
#pragma unroll
        for (int p = 0; p < 2; p++) {
            int s = p * 256 + wv * 64 + lane;
            int c = s >> 3, op = s & 7;
            g2l16(Wt + ((size_t)col0 + c) * 1152 + kc + ((op ^ (c & 7)) << 3),
                  (void*)(s_W + (p * 256 + wv * 64) * 8));
        }
        __syncthreads();
#pragma unroll
        for (int ks = 0; ks < 2; ks++) {
            int o = ks * 4 + quad;
            bf16x8 av = *(const bf16x8*)&s_X[swz(rw * 16 + l15, o)];
#pragma unroll
            for (int cf = 0; cf < 2; cf++) {
                bf16x8 bv = *(const bf16x8*)&s_W[swz(cw * 32 + cf * 16 + l15, o)];
                acc[cf] = MFMA_16x16x32(av, bv, acc[cf]);
            }
        }
    }
#pragma unroll
    for (int cf = 0; cf < 2; cf++) {
        int col = col0 + cw * 32 + cf * 16 + l15;
        float bs = bias[col], gg = bng[col], bb = bnb[col];
        float h0 = gg * tanhf(acc[cf][0] + bs) + bb;
        float h1 = gg * tanhf(acc[cf][1] + bs) + bb;
        float h2 = gg * tanhf(acc[cf][2] + bs) + bb;
        float h3 = gg * tanhf(acc[cf][3] + bs) + bb;
        float p0 = 0.5f * (h0 + h1), p1 = 0.5f * (h2 + h3);
        size_t pr = (size_t)(row0 >> 1) + rw * 8 + quad * 2;
        H1p[pr * 256 + col] = p0;
        H1p[(pr + 1) * 256 + col] = p1;
    }
}

// ---------------------------------------------------------------------------
// FC split-K: grid 512 = 4 col-splits x 128 k-splits (m-chunks of 256).
// ---------------------------------------------------------------------------
__global__ __launch_bounds__(256)
void fc_partial_kernel(const float* __restrict__ Flat, const float* __restrict__ W,
                       float* __restrict__ P) {
    int cs = blockIdx.x & 3, ks = blockIdx.x >> 2;
    int m0 = ks * 256;
    int c4 = threadIdx.x & 31;
    int msub = threadIdx.x >> 5;

    __shared__ __align__(16) float xT[256][16];

#pragma unroll
    for (int q = 0; q < 16; q++) {
        int idx = q * 256 + threadIdx.x;
        int b = idx >> 8, mm = idx & 255;
        int bg = (b >> 2) ^ (mm & 3);
        xT[mm][(bg << 2) + (b & 3)] = Flat[(size_t)b * 32768 + m0 + mm];
    }
    __syncthreads();

    const float4* W4 = (const float4*)W;
    float4 acc[16] = {};

    for (int h = 0; h < 4; h++) {
        float4 wbuf[8];
#pragma unroll
        for (int i = 0; i < 8; i++) {
            int mm = msub * 32 + h * 8 + i;
            wbuf[i] = W4[(size_t)(m0 + mm) * 128 + cs * 32 + c4];
        }
#pragma unroll
        for (int i = 0; i < 8; i++) {
            int mm = msub * 32 + h * 8 + i;
#pragma unroll
            for (int bg = 0; bg < 4; bg++) {
                float4 xv = *(const float4*)&xT[mm][((bg ^ (mm & 3)) << 2)];
                acc[bg * 4 + 0].x += xv.x * wbuf[i].x; acc[bg * 4 + 0].y += xv.x * wbuf[i].y;
                acc[bg * 4 + 0].z += xv.x * wbuf[i].z; acc[bg * 4 + 0].w += xv.x * wbuf[i].w;
                acc[bg * 4 + 1].x += xv.y * wbuf[i].x; acc[bg * 4 + 1].y += xv.y * wbuf[i].y;
                acc[bg * 4 + 1].z += xv.y * wbuf[i].z; acc[bg * 4 + 1].w += xv.y * wbuf[i].w;
                acc[bg * 4 + 2].x += xv.z * wbuf[i].x; acc[bg * 4 + 2].y += xv.z * wbuf[i].y;
                acc[bg * 4 + 2].z += xv.z * wbuf[i].z; acc[bg * 4 + 2].w += xv.z * wbuf[i].w;
                acc[bg * 4 + 3].x += xv.w * wbuf[i].x; acc[bg * 4 + 3].y += xv.w * wbuf[i].y;
                acc[bg * 4 + 3].z += xv.w * wbuf[i].z; acc[bg * 4 + 3].w += xv.w * wbuf[i].w;
            }
        }
    }
    __syncthreads();
    __shared__ __align__(16) float red[8][32][4];
#pragma unroll
    for (int b = 0; b < 16; b++) {
        red[msub][c4][0] = acc[b].x; red[msub][c4][1] = acc[b].y;
        red[msub][c4][2] = acc[b].z; red[msub][c4][3] = acc[b].w;
        __syncthreads();
        if (msub == 0) {
            float4 s = make_float4(0.f, 0.f, 0.f, 0.f);
#pragma unroll
            for (int m = 0; m < 8; m++) {
                s.x += red[m][c4][0]; s.y += red[m][c4][1];
                s.z += red[m][c4][2]; s.w += red[m][c4][3];
            }
            *(float4*)&P[((size_t)ks * 16 + b) * 512 + cs * 128 + c4 * 4] = s;
        }
        __syncthreads();
    }
}

__global__ void fc_reduce_kernel(const float* __restrict__ P, const float* __restrict__ fcb,
                                 float* __restrict__ out) {
    int idx = blockIdx.x * 256 + threadIdx.x;   // 8192 outputs
    float s0 = 0.f, s1 = 0.f;
#pragma unroll 8
    for (int ks = 0; ks < 128; ks += 2) {
        s0 += P[(size_t)ks * 8192 + idx];
        s1 += P[(size_t)(ks + 1) * 8192 + idx];
    }
    float s = s0 + s1 + fcb[idx & 511];
    out[idx] = 1.f / (1.f + expf(-s));
}

// ---------------------------------------------------------------------------
extern "C" void kernel_launch(void* const* d_in, const int* in_sizes, int n_in,
                              void* d_out, int out_size, void* d_ws, size_t ws_size,
                              hipStream_t stream) {
    const float* V     = (const float*)d_in[0];
    const float* C     = (const float*)d_in[1];
    const float* gk_w0 = (const float*)d_in[2];
    const float* gk_b0 = (const float*)d_in[3];
    const float* ac_w0 = (const float*)d_in[4];
    const float* ac_b0 = (const float*)d_in[5];
    const float* gc_w0 = (const float*)d_in[6];
    const float* gc_b0 = (const float*)d_in[7];
    const float* bn_g0 = (const float*)d_in[8];
    const float* bn_b0 = (const float*)d_in[9];
    const float* gk_w1 = (const float*)d_in[10];
    const float* gk_b1 = (const float*)d_in[11];
    const float* ac_w1 = (const float*)d_in[12];
    const float* ac_b1 = (const float*)d_in[13];
    const float* gc_w1 = (const float*)d_in[14];
    const float* gc_b1 = (const float*)d_in[15];
    const float* bn_g1 = (const float*)d_in[16];
    const float* bn_b1 = (const float*)d_in[17];
    const float* fc_w  = (const float*)d_in[18];
    const float* fc_b  = (const float*)d_in[19];
    float* out = (float*)d_out;

    float* H0p = (float*)d_ws;        // 524288
    float* H1p = H0p + 524288;        // 524288
    u16* X0  = (u16*)(H1p + 524288);  // 4718592  [8192][576]
    u16* X1  = X0 + 4718592;          // 4718592  [4096][1152]
    u16* VT0 = X1 + 4718592;          // 524288   [16][64][512]; aliased as VT1
    u16* Wt0 = VT0 + 524288;          // 73728    [128][576]
    u16* Wt1 = Wt0 + 73728;           // 294912   [256][1152]
    u16* VT1 = VT0;  // msg0 finishes with VT0 before t_h0p writes (stream order)
    float* P = (float*)X0;  // 128*16*512 fp32 partials alias X0 (dead after post0)

    prep_kernel<<<346, 256, 0, stream>>>(V, gc_w0, gc_w1, VT0, Wt0, Wt1, X0);
    msg0_mfma<<<512, 256, 0, stream>>>(VT0, C, V, gk_w0, gk_b0, ac_w0, ac_b0, X0);
    post0_mfma<<<512, 256, 0, stream>>>(X0, Wt0, gc_b0, bn_g0, bn_b0, H0p, X1);
    t_h0p_kernel<<<128, 256, 0, stream>>>(H0p, VT1);
    msg1_mfma<<<512, 256, 0, stream>>>(VT1, C, H0p, gk_w1, gk_b1, ac_w1, ac_b1, X1);
    post1_mfma<<<512, 256, 0, stream>>>(X1, Wt1, gc_b1, bn_g1, bn_b1, H1p);
    fc_partial_kernel<<<512, 256, 0, stream>>>(H1p, fc_w, P);
    fc_reduce_kernel<<<32, 256, 0, stream>>>(P, fc_b, out);
}

// Round 6
// 215.272 us; speedup vs baseline: 2.7726x; 1.0421x over previous
//
#include <hip/hip_runtime.h>
#include <math.h>

#define KK 8
#define EPSF 1e-9f

typedef unsigned int   uint32;
typedef unsigned short u16;
typedef __attribute__((ext_vector_type(8))) short bf16x8;
typedef __attribute__((ext_vector_type(4))) float f32x4;

#define MFMA_16x16x32(a, b, c) __builtin_amdgcn_mfma_f32_16x16x32_bf16(a, b, c, 0, 0, 0)

typedef __attribute__((address_space(1))) const unsigned int glob_cu32;
typedef __attribute__((address_space(3))) unsigned int lds_u32;
// async global->LDS DMA, 16B per lane; LDS dest = wave-uniform base + lane*16
__device__ __forceinline__ void g2l16(const void* gsrc, void* ldst) {
    __builtin_amdgcn_global_load_lds((glob_cu32*)gsrc, (lds_u32*)ldst, 16, 0, 0);
}

// swizzled ushort index of logical octet o (8 bf16) in a [row][64] LDS tile
__device__ __forceinline__ int swz(int row, int o) {
    return (row << 6) + (((o) ^ (row & 7)) << 3);
}

__device__ __forceinline__ float softplusf(float x) {
    return x > 0.0f ? x + log1pf(expf(-x)) : log1pf(expf(x));
}
__device__ __forceinline__ float sigmoidf_(float x) {
    return 1.0f / (1.0f + expf(-x));
}
// fp32 -> bf16 round-to-nearest-even
__device__ __forceinline__ u16 f2bf(float f) {
    union { float f; uint32 u; } v; v.f = f;
    uint32 u = v.u;
    return (u16)((u + 0x7FFFu + ((u >> 16) & 1u)) >> 16);
}

// ---------------------------------------------------------------------------
// prep: V->VT0 bf16 [16][64][512] (transposed), gc_w0->Wt0 bf16 [128][576],
//       gc_w1->Wt1 bf16 [256][1152].
// ---------------------------------------------------------------------------
__global__ __launch_bounds__(256)
void prep_kernel(const float* __restrict__ V, const float* __restrict__ W0,
                 const float* __restrict__ W1, u16* __restrict__ VT0,
                 u16* __restrict__ Wt0, u16* __restrict__ Wt1) {
    __shared__ float s[64][65];
    int blk = blockIdx.x, tid = threadIdx.x;
    if (blk < 128) {            // V [16][512][64] -> VT0 [16][64][512]
        int b = blk >> 3, rt = blk & 7;
#pragma unroll
        for (int t = 0; t < 16; t++) {
            int idx = t * 256 + tid; int r = idx >> 6, c = idx & 63;
            s[r][c] = V[((size_t)b * 512 + rt * 64 + r) * 64 + c];
        }
        __syncthreads();
#pragma unroll
        for (int t = 0; t < 16; t++) {
            int idx = t * 256 + tid; int f = idx >> 6, j = idx & 63;
            VT0[((size_t)b * 64 + f) * 512 + rt * 64 + j] = f2bf(s[j][f]);
        }
    } else if (blk < 146) {     // W0 [576][128] -> Wt0 [128][576]
        int t0 = blk - 128; int rt = t0 >> 1, ct = t0 & 1;
#pragma unroll
        for (int t = 0; t < 16; t++) {
            int idx = t * 256 + tid; int r = idx >> 6, c = idx & 63;
            s[r][c] = W0[((size_t)rt * 64 + r) * 128 + ct * 64 + c];
        }
        __syncthreads();
#pragma unroll
        for (int t = 0; t < 16; t++) {
            int idx = t * 256 + tid; int f = idx >> 6, j = idx & 63;
            Wt0[((size_t)ct * 64 + f) * 576 + rt * 64 + j] = f2bf(s[j][f]);
        }
    } else {                    // W1 [1152][256] -> Wt1 [256][1152]
        int t0 = blk - 146; int rt = t0 >> 2, ct = t0 & 3;
#pragma unroll
        for (int t = 0; t < 16; t++) {
            int idx = t * 256 + tid; int r = idx >> 6, c = idx & 63;
            s[r][c] = W1[((size_t)rt * 64 + r) * 256 + ct * 64 + c];
        }
        __syncthreads();
#pragma unroll
        for (int t = 0; t < 16; t++) {
            int idx = t * 256 + tid; int f = idx >> 6, j = idx & 63;
            Wt1[((size_t)ct * 64 + f) * 1152 + rt * 64 + j] = f2bf(s[j][f]);
        }
    }
}

// ---------------------------------------------------------------------------
// layer0_fused: per block = 16 node-rows of one batch.
//   A: uw (fused GraphKernels/AngularContribution row-proj), ci, V->s_X[:, :64]
//   B: j-loop (8x64): A-gen -> s_A, DMA V^T -> s_vT, msg MFMA acc[2][4]
//   C: acc -> s_X[:, 64:576] (concat tile in LDS)
//   D: mini-GEMM [16x576]@[576x128] vs DMA-staged Wt0 (LDS union with B bufs)
//   E: tanh/bn/pool -> H0p fp32 + VT1 bf16 (transposed)
// Grid 512 = 16 b x 32 tiles. LDS ~44 KB -> 3 blocks/CU cap.
// ---------------------------------------------------------------------------
__global__ __launch_bounds__(256)
void layer0_fused(const u16* __restrict__ VT0, const float* __restrict__ C,
                  const float* __restrict__ V,
                  const float* __restrict__ gw, const float* __restrict__ gb,
                  const float* __restrict__ aw, const float* __restrict__ ab,
                  const u16* __restrict__ Wt0, const float* __restrict__ bias,
                  const float* __restrict__ bng, const float* __restrict__ bnb,
                  float* __restrict__ H0p, u16* __restrict__ VT1) {
    int b = blockIdx.x >> 5, tile = blockIdx.x & 31;
    int i0 = tile * 16;
    int tid = threadIdx.x;
    int wv = tid >> 6, lane = tid & 63, quad = lane >> 4, l15 = lane & 15;

    __shared__ __align__(16) u16 s_mem[12288];   // union: [s_vT 4096 | s_A 8192] / s_W 8192
    __shared__ __align__(16) u16 s_X[16 * 584];  // 18.7 KB, stride 584 (+8 pad)
    __shared__ __align__(16) float s_ci[16][4];
    __shared__ float s_u[16][KK];
    __shared__ float s_w[16][KK];

    u16* s_vT = s_mem;
    u16* s_A  = s_mem + 4096;
    u16* s_W  = s_mem;

    // ---- phase A ----
    {
        int t = tid & 127;
        int i = t >> 3, k = t & 7;
        const float4* xr = (const float4*)(V + ((size_t)b * 512 + i0 + i) * 64);
        const float* wm = (tid < 128) ? gw : aw;
        float s = 0.f;
#pragma unroll
        for (int f4 = 0; f4 < 16; f4++) {
            float4 x = xr[f4];
            s += x.x * wm[(f4 * 4 + 0) * 8 + k] + x.y * wm[(f4 * 4 + 1) * 8 + k]
               + x.z * wm[(f4 * 4 + 2) * 8 + k] + x.w * wm[(f4 * 4 + 3) * 8 + k];
        }
        if (tid < 128) s_u[i][k] = softplusf(s + gb[k]);
        else           s_w[i][k] = sigmoidf_(s + ab[k]);
    }
    if (tid < 16) {
        const float* cp = C + ((size_t)b * 512 + i0 + tid) * 3;
        float x = cp[0], y = cp[1], z = cp[2];
        s_ci[tid][0] = x; s_ci[tid][1] = y; s_ci[tid][2] = z;
        s_ci[tid][3] = x * x + y * y + z * z;
    }
    {   // V rows -> s_X cols 0..63 (bf16)
        int row = tid >> 4, f4 = tid & 15;
        float4 x = *(const float4*)(V + ((size_t)b * 512 + i0 + row) * 64 + f4 * 4);
        *(uint32*)&s_X[row * 584 + f4 * 4]     = (uint32)f2bf(x.x) | ((uint32)f2bf(x.y) << 16);
        *(uint32*)&s_X[row * 584 + f4 * 4 + 2] = (uint32)f2bf(x.z) | ((uint32)f2bf(x.w) << 16);
    }

    // ---- phase B: msg K-loop ----
    f32x4 acc[2][4] = {};
    for (int j0 = 0; j0 < 512; j0 += 64) {
        const float* cp = C + ((size_t)b * 512 + j0 + lane) * 3;
        float cjx = cp[0], cjy = cp[1], cjz = cp[2];
        float l2j = cjx * cjx + cjy * cjy + cjz * cjz;
        __syncthreads();               // prev-iter MFMA reads drained (also covers phase A)
#pragma unroll
        for (int p = 0; p < 2; p++) {  // DMA V^T tile [64 f][64 j]
            int s = p * 256 + wv * 64 + lane;
            int f = s >> 3, op = s & 7;
            g2l16(VT0 + ((size_t)b * 64 + f) * 512 + j0 + ((op ^ (f & 7)) << 3),
                  (void*)(s_vT + (p * 256 + wv * 64) * 8));
        }
#pragma unroll
        for (int t = 0; t < 4; t++) {  // A-gen: (i = t*4+wv, j = lane), 8 k
            int i = t * 4 + wv, j = lane;
            float dot = s_ci[i][0] * cjx + s_ci[i][1] * cjy + s_ci[i][2] * cjz;
            float d2 = fabsf(s_ci[i][3] + l2j - 2.f * dot) + EPSF;
            float cs = dot / sqrtf((s_ci[i][3] + EPSF) * (l2j + EPSF));
            f32x4 u01 = *(const f32x4*)&s_u[i][0];
            f32x4 u23 = *(const f32x4*)&s_u[i][4];
            f32x4 w01 = *(const f32x4*)&s_w[i][0];
            f32x4 w23 = *(const f32x4*)&s_w[i][4];
#pragma unroll
            for (int k = 0; k < 4; k++) {
                float a = __expf(-d2 * u01[k]) * (w01[k] * cs + 1.f - w01[k]);
                int row = i * 8 + k;
                s_A[(row << 6) + (((j >> 3) ^ (row & 7)) << 3) + (j & 7)] = f2bf(a);
            }
#pragma unroll
            for (int k = 0; k < 4; k++) {
                float a = __expf(-d2 * u23[k]) * (w23[k] * cs + 1.f - w23[k]);
                int row = i * 8 + 4 + k;
                s_A[(row << 6) + (((j >> 3) ^ (row & 7)) << 3) + (j & 7)] = f2bf(a);
            }
        }
        __syncthreads();               // DMA + A-writes visible
#pragma unroll
        for (int ks = 0; ks < 2; ks++) {
            int o = ks * 4 + quad;
            bf16x8 a0 = *(const bf16x8*)&s_A[swz(wv * 32 + l15, o)];
            bf16x8 a1 = *(const bf16x8*)&s_A[swz(wv * 32 + 16 + l15, o)];
#pragma unroll
            for (int cf = 0; cf < 4; cf++) {
                bf16x8 bv = *(const bf16x8*)&s_vT[swz(cf * 16 + l15, o)];
                acc[0][cf] = MFMA_16x16x32(a0, bv, acc[0][cf]);
                acc[1][cf] = MFMA_16x16x32(a1, bv, acc[1][cf]);
            }
        }
    }

    // ---- phase C: msg acc -> s_X cols 64..575 ----
#pragma unroll
    for (int rf = 0; rf < 2; rf++)
#pragma unroll
        for (int cf = 0; cf < 4; cf++)
#pragma unroll
            for (int r = 0; r < 4; r++) {
                int arow = wv * 32 + rf * 16 + quad * 4 + r;
                int i = arow >> 3, k = arow & 7;
                s_X[i * 584 + 64 + k * 64 + cf * 16 + l15] = f2bf(acc[rf][cf][r]);
            }

    // ---- phase D: mini-GEMM [16 x 576] @ Wt0^T, 9 chunks of 64 ----
    f32x4 acc2[2] = {};
    for (int kc = 0; kc < 576; kc += 64) {
        __syncthreads();               // s_mem free (prev MFMA reads done); C-writes ordered
#pragma unroll
        for (int p = 0; p < 4; p++) {  // DMA Wt0 chunk [128 c][64 k]
            int s = p * 256 + wv * 64 + lane;
            int c = s >> 3, op = s & 7;
            g2l16(Wt0 + (size_t)c * 576 + kc + ((op ^ (c & 7)) << 3),
                  (void*)(s_W + (p * 256 + wv * 64) * 8));
        }
        __syncthreads();
#pragma unroll
        for (int ks = 0; ks < 2; ks++) {
            int o = ks * 4 + quad;
            bf16x8 av = *(const bf16x8*)&s_X[l15 * 584 + kc + o * 8];
#pragma unroll
            for (int cf = 0; cf < 2; cf++) {
                bf16x8 bv = *(const bf16x8*)&s_W[swz(wv * 32 + cf * 16 + l15, o)];
                acc2[cf] = MFMA_16x16x32(av, bv, acc2[cf]);
            }
        }
    }

    // ---- phase E: tanh/bn/pool -> H0p + transposed VT1 ----
#pragma unroll
    for (int cf = 0; cf < 2; cf++) {
        int col = wv * 32 + cf * 16 + l15;
        float bs = bias[col], gg = bng[col], bb = bnb[col];
        float h0 = gg * tanhf(acc2[cf][0] + bs) + bb;
        float h1 = gg * tanhf(acc2[cf][1] + bs) + bb;
        float h2 = gg * tanhf(acc2[cf][2] + bs) + bb;
        float h3 = gg * tanhf(acc2[cf][3] + bs) + bb;
        float p0 = 0.5f * (h0 + h1), p1 = 0.5f * (h2 + h3);
        int pl = tile * 8 + quad * 2;          // local pooled row within b (0..255)
        H0p[((size_t)b * 256 + pl) * 128 + col] = p0;
        H0p[((size_t)b * 256 + pl + 1) * 128 + col] = p1;
        VT1[((size_t)b * 128 + col) * 256 + pl]     = f2bf(p0);
        VT1[((size_t)b * 128 + col) * 256 + pl + 1] = f2bf(p1);
    }
}

// ---------------------------------------------------------------------------
// layer1_fused: per block = 8 pooled-node rows of one batch.
// Same 5 phases; coords pooled inline from C; A rows = 64 (8i x 8k);
// mini-GEMM [8(padded 16) x 1152] @ Wt1^T -> 256 cols -> pool -> H1p.
// Grid 512 = 16 b x 32 tiles. LDS ~51 KB -> 3 blocks/CU cap.
// ---------------------------------------------------------------------------
__global__ __launch_bounds__(256)
void layer1_fused(const u16* __restrict__ VT1, const float* __restrict__ C,
                  const float* __restrict__ H0p,
                  const float* __restrict__ gw, const float* __restrict__ gb,
                  const float* __restrict__ aw, const float* __restrict__ ab,
                  const u16* __restrict__ Wt1, const float* __restrict__ bias,
                  const float* __restrict__ bng, const float* __restrict__ bnb,
                  float* __restrict__ H1p) {
    int b = blockIdx.x >> 5, tile = blockIdx.x & 31;
    int i0 = tile * 8;
    int tid = threadIdx.x;
    int wv = tid >> 6, lane = tid & 63, quad = lane >> 4, l15 = lane & 15;

    __shared__ __align__(16) u16 s_mem[16384];   // union: [s_vT 8192 | s_A 8192] / s_W 16384
    __shared__ __align__(16) u16 s_X1[8 * 1160]; // 18.6 KB, stride 1160 (+8 pad)
    __shared__ __align__(16) float s_ci[8][4];
    __shared__ float s_u[8][KK];
    __shared__ float s_w[8][KK];

    u16* s_vT = s_mem;
    u16* s_A  = s_mem + 8192;
    u16* s_W  = s_mem;

    // ---- phase A ----
    if (wv < 2) {   // uw over H0p rows (F=128): wv0 -> u, wv1 -> w
        int t = tid & 63;
        int i = t >> 3, k = t & 7;
        const float4* xr = (const float4*)(H0p + ((size_t)b * 256 + i0 + i) * 128);
        const float* wm = (wv == 0) ? gw : aw;
        float s = 0.f;
#pragma unroll
        for (int f4 = 0; f4 < 32; f4++) {
            float4 x = xr[f4];
            s += x.x * wm[(f4 * 4 + 0) * 8 + k] + x.y * wm[(f4 * 4 + 1) * 8 + k]
               + x.z * wm[(f4 * 4 + 2) * 8 + k] + x.w * wm[(f4 * 4 + 3) * 8 + k];
        }
        if (wv == 0) s_u[i][k] = softplusf(s + gb[k]);
        else         s_w[i][k] = sigmoidf_(s + ab[k]);
    }
    if (tid < 8) {  // pooled coords
        const float* cp = C + ((size_t)b * 512 + 2 * (i0 + tid)) * 3;
        float x = 0.5f * (cp[0] + cp[3]);
        float y = 0.5f * (cp[1] + cp[4]);
        float z = 0.5f * (cp[2] + cp[5]);
        s_ci[tid][0] = x; s_ci[tid][1] = y; s_ci[tid][2] = z;
        s_ci[tid][3] = x * x + y * y + z * z;
    }
    {   // H0p rows -> s_X1 cols 0..127 (bf16)
        int row = tid >> 5, f4 = tid & 31;
        float4 x = *(const float4*)(H0p + ((size_t)b * 256 + i0 + row) * 128 + f4 * 4);
        *(uint32*)&s_X1[row * 1160 + f4 * 4]     = (uint32)f2bf(x.x) | ((uint32)f2bf(x.y) << 16);
        *(uint32*)&s_X1[row * 1160 + f4 * 4 + 2] = (uint32)f2bf(x.z) | ((uint32)f2bf(x.w) << 16);
    }

    // ---- phase B: msg K-loop (4 x 64 j) ----
    f32x4 acc[8] = {};
    for (int j0 = 0; j0 < 256; j0 += 64) {
        const float* cp = C + ((size_t)b * 512 + 2 * (j0 + lane)) * 3;
        float cjx = 0.5f * (cp[0] + cp[3]);
        float cjy = 0.5f * (cp[1] + cp[4]);
        float cjz = 0.5f * (cp[2] + cp[5]);
        float l2j = cjx * cjx + cjy * cjy + cjz * cjz;
        __syncthreads();
#pragma unroll
        for (int p = 0; p < 4; p++) {  // DMA H^T tile [128 f][64 j]
            int s = p * 256 + wv * 64 + lane;
            int f = s >> 3, op = s & 7;
            g2l16(VT1 + ((size_t)b * 128 + f) * 256 + j0 + ((op ^ (f & 7)) << 3),
                  (void*)(s_vT + (p * 256 + wv * 64) * 8));
        }
#pragma unroll
        for (int t = 0; t < 2; t++) {  // A-gen: (i = t*4+wv in 0..7, j = lane), 8 k
            int i = t * 4 + wv, j = lane;
            float dot = s_ci[i][0] * cjx + s_ci[i][1] * cjy + s_ci[i][2] * cjz;
            float d2 = fabsf(s_ci[i][3] + l2j - 2.f * dot) + EPSF;
            float cs = dot / sqrtf((s_ci[i][3] + EPSF) * (l2j + EPSF));
            f32x4 u01 = *(const f32x4*)&s_u[i][0];
            f32x4 u23 = *(const f32x4*)&s_u[i][4];
            f32x4 w01 = *(const f32x4*)&s_w[i][0];
            f32x4 w23 = *(const f32x4*)&s_w[i][4];
#pragma unroll
            for (int k = 0; k < 4; k++) {
                float a = __expf(-d2 * u01[k]) * (w01[k] * cs + 1.f - w01[k]);
                int row = i * 8 + k;
                s_A[(row << 6) + (((j >> 3) ^ (row & 7)) << 3) + (j & 7)] = f2bf(a);
            }
#pragma unroll
            for (int k = 0; k < 4; k++) {
                float a = __expf(-d2 * u23[k]) * (w23[k] * cs + 1.f - w23[k]);
                int row = i * 8 + 4 + k;
                s_A[(row << 6) + (((j >> 3) ^ (row & 7)) << 3) + (j & 7)] = f2bf(a);
            }
        }
        __syncthreads();
#pragma unroll
        for (int ks = 0; ks < 2; ks++) {
            int o = ks * 4 + quad;
            bf16x8 a0 = *(const bf16x8*)&s_A[swz(wv * 16 + l15, o)];
#pragma unroll
            for (int cf = 0; cf < 8; cf++) {
                bf16x8 bv = *(const bf16x8*)&s_vT[swz(cf * 16 + l15, o)];
                acc[cf] = MFMA_16x16x32(a0, bv, acc[cf]);
            }
        }
    }

    // ---- phase C: msg acc -> s_X1 cols 128..1151 ----
#pragma unroll
    for (int cf = 0; cf < 8; cf++)
#pragma unroll
        for (int r = 0; r < 4; r++) {
            int arow = wv * 16 + quad * 4 + r;
            int i = arow >> 3, k = arow & 7;
            s_X1[i * 1160 + 128 + k * 128 + cf * 16 + l15] = f2bf(acc[cf][r]);
        }

    // ---- phase D: mini-GEMM [8 x 1152] @ Wt1^T, 18 chunks of 64 ----
    f32x4 acc2[4] = {};
    for (int kc = 0; kc < 1152; kc += 64) {
        __syncthreads();
#pragma unroll
        for (int p = 0; p < 8; p++) {  // DMA Wt1 chunk [256 c][64 k]
            int s = p * 256 + wv * 64 + lane;
            int c = s >> 3, op = s & 7;
            g2l16(Wt1 + (size_t)c * 1152 + kc + ((op ^ (c & 7)) << 3),
                  (void*)(s_W + (p * 256 + wv * 64) * 8));
        }
        __syncthreads();
#pragma unroll
        for (int ks = 0; ks < 2; ks++) {
            int o = ks * 4 + quad;
            bf16x8 av = *(const bf16x8*)&s_X1[(l15 & 7) * 1160 + kc + o * 8];  // rows 8..15 dup (discarded)
#pragma unroll
            for (int cf = 0; cf < 4; cf++) {
                bf16x8 bv = *(const bf16x8*)&s_W[swz(wv * 64 + cf * 16 + l15, o)];
                acc2[cf] = MFMA_16x16x32(av, bv, acc2[cf]);
            }
        }
    }

    // ---- phase E: tanh/bn/pool -> H1p (valid C rows 0..7 -> quads 0,1) ----
#pragma unroll
    for (int cf = 0; cf < 4; cf++) {
        int col = wv * 64 + cf * 16 + l15;
        float bs = bias[col], gg = bng[col], bb = bnb[col];
        float h0 = gg * tanhf(acc2[cf][0] + bs) + bb;
        float h1 = gg * tanhf(acc2[cf][1] + bs) + bb;
        float h2 = gg * tanhf(acc2[cf][2] + bs) + bb;
        float h3 = gg * tanhf(acc2[cf][3] + bs) + bb;
        if (quad < 2) {
            float p0 = 0.5f * (h0 + h1), p1 = 0.5f * (h2 + h3);
            int pl = tile * 4 + quad * 2;      // local pooled row within b (0..127)
            H1p[((size_t)b * 128 + pl) * 256 + col] = p0;
            H1p[((size_t)b * 128 + pl + 1) * 256 + col] = p1;
        }
    }
}

// ---------------------------------------------------------------------------
// FC split-K: grid 512 = 4 col-splits x 128 k-splits (m-chunks of 256).
// ---------------------------------------------------------------------------
__global__ __launch_bounds__(256)
void fc_partial_kernel(const float* __restrict__ Flat, const float* __restrict__ W,
                       float* __restrict__ P) {
    int cs = blockIdx.x & 3, ks = blockIdx.x >> 2;
    int m0 = ks * 256;
    int c4 = threadIdx.x & 31;
    int msub = threadIdx.x >> 5;

    __shared__ __align__(16) float xT[256][16];

#pragma unroll
    for (int q = 0; q < 16; q++) {
        int idx = q * 256 + threadIdx.x;
        int b = idx >> 8, mm = idx & 255;
        int bg = (b >> 2) ^ (mm & 3);
        xT[mm][(bg << 2) + (b & 3)] = Flat[(size_t)b * 32768 + m0 + mm];
    }
    __syncthreads();

    const float4* W4 = (const float4*)W;
    float4 acc[16] = {};

    for (int h = 0; h < 4; h++) {
        float4 wbuf[8];
#pragma unroll
        for (int i = 0; i < 8; i++) {
            int mm = msub * 32 + h * 8 + i;
            wbuf[i] = W4[(size_t)(m0 + mm) * 128 + cs * 32 + c4];
        }
#pragma unroll
        for (int i = 0; i < 8; i++) {
            int mm = msub * 32 + h * 8 + i;
#pragma unroll
            for (int bg = 0; bg < 4; bg++) {
                float4 xv = *(const float4*)&xT[mm][((bg ^ (mm & 3)) << 2)];
                acc[bg * 4 + 0].x += xv.x * wbuf[i].x; acc[bg * 4 + 0].y += xv.x * wbuf[i].y;
                acc[bg * 4 + 0].z += xv.x * wbuf[i].z; acc[bg * 4 + 0].w += xv.x * wbuf[i].w;
                acc[bg * 4 + 1].x += xv.y * wbuf[i].x; acc[bg * 4 + 1].y += xv.y * wbuf[i].y;
                acc[bg * 4 + 1].z += xv.y * wbuf[i].z; acc[bg * 4 + 1].w += xv.y * wbuf[i].w;
                acc[bg * 4 + 2].x += xv.z * wbuf[i].x; acc[bg * 4 + 2].y += xv.z * wbuf[i].y;
                acc[bg * 4 + 2].z += xv.z * wbuf[i].z; acc[bg * 4 + 2].w += xv.z * wbuf[i].w;
                acc[bg * 4 + 3].x += xv.w * wbuf[i].x; acc[bg * 4 + 3].y += xv.w * wbuf[i].y;
                acc[bg * 4 + 3].z += xv.w * wbuf[i].z; acc[bg * 4 + 3].w += xv.w * wbuf[i].w;
            }
        }
    }
    __syncthreads();
    __shared__ __align__(16) float red[8][32][4];
#pragma unroll
    for (int b = 0; b < 16; b++) {
        red[msub][c4][0] = acc[b].x; red[msub][c4][1] = acc[b].y;
        red[msub][c4][2] = acc[b].z; red[msub][c4][3] = acc[b].w;
        __syncthreads();
        if (msub == 0) {
            float4 s = make_float4(0.f, 0.f, 0.f, 0.f);
#pragma unroll
            for (int m = 0; m < 8; m++) {
                s.x += red[m][c4][0]; s.y += red[m][c4][1];
                s.z += red[m][c4][2]; s.w += red[m][c4][3];
            }
            *(float4*)&P[((size_t)ks * 16 + b) * 512 + cs * 128 + c4 * 4] = s;
        }
        __syncthreads();
    }
}

__global__ void fc_reduce_kernel(const float* __restrict__ P, const float* __restrict__ fcb,
                                 float* __restrict__ out) {
    int idx = blockIdx.x * 256 + threadIdx.x;   // 8192 outputs
    float s0 = 0.f, s1 = 0.f;
#pragma unroll 8
    for (int ks = 0; ks < 128; ks += 2) {
        s0 += P[(size_t)ks * 8192 + idx];
        s1 += P[(size_t)(ks + 1) * 8192 + idx];
    }
    float s = s0 + s1 + fcb[idx & 511];
    out[idx] = 1.f / (1.f + expf(-s));
}

// ---------------------------------------------------------------------------
extern "C" void kernel_launch(void* const* d_in, const int* in_sizes, int n_in,
                              void* d_out, int out_size, void* d_ws, size_t ws_size,
                              hipStream_t stream) {
    const float* V     = (const float*)d_in[0];
    const float* C     = (const float*)d_in[1];
    const float* gk_w0 = (const float*)d_in[2];
    const float* gk_b0 = (const float*)d_in[3];
    const float* ac_w0 = (const float*)d_in[4];
    const float* ac_b0 = (const float*)d_in[5];
    const float* gc_w0 = (const float*)d_in[6];
    const float* gc_b0 = (const float*)d_in[7];
    const float* bn_g0 = (const float*)d_in[8];
    const float* bn_b0 = (const float*)d_in[9];
    const float* gk_w1 = (const float*)d_in[10];
    const float* gk_b1 = (const float*)d_in[11];
    const float* ac_w1 = (const float*)d_in[12];
    const float* ac_b1 = (const float*)d_in[13];
    const float* gc_w1 = (const float*)d_in[14];
    const float* gc_b1 = (const float*)d_in[15];
    const float* bn_g1 = (const float*)d_in[16];
    const float* bn_b1 = (const float*)d_in[17];
    const float* fc_w  = (const float*)d_in[18];
    const float* fc_b  = (const float*)d_in[19];
    float* out = (float*)d_out;

    float* H0p = (float*)d_ws;        // [4096][128] = 524288 f32
    float* H1p = H0p + 524288;        // [2048][256] = 524288 f32
    float* P   = H1p + 524288;        // 128*16*512 = 1048576 f32
    u16* VT0 = (u16*)(P + 1048576);   // [16][64][512]  = 524288 u16
    u16* VT1 = VT0 + 524288;          // [16][128][256] = 524288 u16
    u16* Wt0 = VT1 + 524288;          // [128][576]  = 73728 u16
    u16* Wt1 = Wt0 + 73728;           // [256][1152] = 294912 u16

    prep_kernel<<<218, 256, 0, stream>>>(V, gc_w0, gc_w1, VT0, Wt0, Wt1);
    layer0_fused<<<512, 256, 0, stream>>>(VT0, C, V, gk_w0, gk_b0, ac_w0, ac_b0,
                                          Wt0, gc_b0, bn_g0, bn_b0, H0p, VT1);
    layer1_fused<<<512, 256, 0, stream>>>(VT1, C, H0p, gk_w1, gk_b1, ac_w1, ac_b1,
                                          Wt1, gc_b1, bn_g1, bn_b1, H1p);
    fc_partial_kernel<<<512, 256, 0, stream>>>(H1p, fc_w, P);
    fc_reduce_kernel<<<32, 256, 0, stream>>>(P, fc_b, out);
}